// Round 1
// baseline (1158.877 us; speedup 1.0000x reference)
//
#include <hip/hip_runtime.h>

// ---------------------------------------------------------------------------
// GCN forward: 3x (dual GEMM -> edge gather-agg -> BN) -> pooled readouts -> MLP head
// All f32. CSR (by dst) built on-device each launch; gather aggregation (no hot atomics).
// ---------------------------------------------------------------------------

#define D128 128

__global__ void k_deg(const int* __restrict__ src, const int* __restrict__ dst,
                      int* __restrict__ dego, int* __restrict__ degi, int E) {
  int e = blockIdx.x * 256 + threadIdx.x;
  if (e < E) {
    atomicAdd(&dego[src[e]], 1);
    atomicAdd(&degi[dst[e]], 1);
  }
}

__global__ void k_norm(const int* __restrict__ dego, const int* __restrict__ degi,
                       float* __restrict__ ns, float* __restrict__ nd, int N) {
  int i = blockIdx.x * 256 + threadIdx.x;
  if (i < N) {
    ns[i] = rsqrtf(fmaxf((float)dego[i], 1.f));
    nd[i] = rsqrtf(fmaxf((float)degi[i], 1.f));
  }
}

// exclusive scan of degi -> rp[0..N], single block
__global__ __launch_bounds__(1024) void k_scan(const int* __restrict__ deg,
                                               int* __restrict__ rp, int N) {
  __shared__ int part[1024];
  int t = threadIdx.x;
  int chunk = (N + 1023) >> 10;
  int b = t * chunk;
  int e = min(b + chunk, N);
  int s = 0;
  for (int i = b; i < e; ++i) s += deg[i];
  part[t] = s;
  __syncthreads();
  for (int off = 1; off < 1024; off <<= 1) {
    int v = (t >= off) ? part[t - off] : 0;
    __syncthreads();
    part[t] += v;
    __syncthreads();
  }
  int run = (t == 0) ? 0 : part[t - 1];
  for (int i = b; i < e; ++i) { rp[i] = run; run += deg[i]; }
  if (t == 1023) rp[N] = run;
}

__global__ void k_csr(const int* __restrict__ src, const int* __restrict__ dst,
                      const int* __restrict__ rp, int* __restrict__ cur,
                      int* __restrict__ csrc, int E) {
  int e = blockIdx.x * 256 + threadIdx.x;
  if (e < E) {
    int d = dst[e];
    int p = atomicAdd(&cur[d], 1);
    csrc[rp[d] + p] = src[e];
  }
}

// hw = (h @ Wg) * norm_src (row scale), res = relu(h @ Wr + br)
// block 256 threads, 32 rows/block; thread: 4 rows x 4 cols x 2 matrices
__global__ __launch_bounds__(256) void k_dualgemm(
    const float* __restrict__ h, const float* __restrict__ Wg,
    const float* __restrict__ Wr, const float* __restrict__ brl,
    const float* __restrict__ ns, float* __restrict__ hw,
    float* __restrict__ res, int N) {
  __shared__ float4 hs[32][32];  // 32 rows x 128 floats
  int t = threadIdx.x;
  int row0 = blockIdx.x * 32;
  for (int i = t; i < 1024; i += 256) {
    int r = i >> 5, c = i & 31;
    int gr = row0 + r;
    float4 v = make_float4(0.f, 0.f, 0.f, 0.f);
    if (gr < N) v = ((const float4*)h)[(size_t)gr * 32 + c];
    hs[r][c] = v;
  }
  __syncthreads();
  const int rb = (t >> 5) * 4;
  const int j0 = (t & 31) * 4;
  float accg[4][4] = {};
  float accr[4][4] = {};
  for (int k4 = 0; k4 < 32; ++k4) {
    float a[4][4];
#pragma unroll
    for (int r = 0; r < 4; ++r) {
      float4 v = hs[rb + r][k4];
      a[r][0] = v.x; a[r][1] = v.y; a[r][2] = v.z; a[r][3] = v.w;
    }
#pragma unroll
    for (int kk = 0; kk < 4; ++kk) {
      int k = k4 * 4 + kk;
      float4 wg = *(const float4*)(Wg + k * D128 + j0);
      float4 wr = *(const float4*)(Wr + k * D128 + j0);
      float wga[4] = {wg.x, wg.y, wg.z, wg.w};
      float wra[4] = {wr.x, wr.y, wr.z, wr.w};
#pragma unroll
      for (int r = 0; r < 4; ++r) {
#pragma unroll
        for (int j = 0; j < 4; ++j) {
          accg[r][j] += a[r][kk] * wga[j];
          accr[r][j] += a[r][kk] * wra[j];
        }
      }
    }
  }
  float4 bb = *(const float4*)(brl + j0);
  float ba[4] = {bb.x, bb.y, bb.z, bb.w};
#pragma unroll
  for (int r = 0; r < 4; ++r) {
    int gr = row0 + rb + r;
    if (gr >= N) continue;
    float s = ns[gr];
    float4 og, orr;
    og.x = accg[r][0] * s; og.y = accg[r][1] * s;
    og.z = accg[r][2] * s; og.w = accg[r][3] * s;
    orr.x = fmaxf(accr[r][0] + ba[0], 0.f);
    orr.y = fmaxf(accr[r][1] + ba[1], 0.f);
    orr.z = fmaxf(accr[r][2] + ba[2], 0.f);
    orr.w = fmaxf(accr[r][3] + ba[3], 0.f);
    *(float4*)(hw + (size_t)gr * D128 + j0) = og;
    *(float4*)(res + (size_t)gr * D128 + j0) = orr;
  }
}

// one wave per node: y = relu(agg*nd + bg) + res, written over res (yres)
__global__ __launch_bounds__(256) void k_agg(
    const float* __restrict__ hw, const int* __restrict__ rp,
    const int* __restrict__ csrc, const float* __restrict__ nd,
    const float* __restrict__ bgl, float* __restrict__ yres, int N) {
  int n = blockIdx.x * 4 + (threadIdx.x >> 6);
  int lane = threadIdx.x & 63;
  if (n >= N) return;
  int beg = rp[n], end = rp[n + 1];
  float ax = 0.f, ay = 0.f;
  for (int e = beg; e < end; ++e) {
    int s = csrc[e];
    float2 v = ((const float2*)hw)[(size_t)s * 64 + lane];
    ax += v.x; ay += v.y;
  }
  float ndv = nd[n];
  float2 b = ((const float2*)bgl)[lane];
  float2 r = ((const float2*)yres)[(size_t)n * 64 + lane];
  float2 y;
  y.x = fmaxf(ax * ndv + b.x, 0.f) + r.x;
  y.y = fmaxf(ay * ndv + b.y, 0.f) + r.y;
  ((float2*)yres)[(size_t)n * 64 + lane] = y;
}

__global__ __launch_bounds__(256) void k_stats(const float* __restrict__ y,
                                               float* __restrict__ s1,
                                               float* __restrict__ s2, int N) {
  int t = threadIdx.x;
  int col = t & 127, half = t >> 7;
  float a = 0.f, q = 0.f;
  for (int r = blockIdx.x * 2 + half; r < N; r += gridDim.x * 2) {
    float v = y[(size_t)r * D128 + col];
    a += v; q += v * v;
  }
  __shared__ float ls[256], lq[256];
  ls[t] = a; lq[t] = q;
  __syncthreads();
  if (t < 128) {
    atomicAdd(&s1[col], ls[t] + ls[t + 128]);
    atomicAdd(&s2[col], lq[t] + lq[t + 128]);
  }
}

__global__ void k_bnfin(const float* __restrict__ s1, const float* __restrict__ s2,
                        const float* __restrict__ gam, const float* __restrict__ bet,
                        float* __restrict__ scale, float* __restrict__ shift, float invN) {
  int j = threadIdx.x;
  float mu = s1[j] * invN;
  float var = s2[j] * invN - mu * mu;
  float sc = gam[j] * rsqrtf(var + 1e-5f);
  scale[j] = sc;
  shift[j] = bet[j] - mu * sc;
}

__global__ void k_bnapply(const float* __restrict__ y, const float* __restrict__ scale,
                          const float* __restrict__ shift, float* __restrict__ h, int N) {
  int i = blockIdx.x * 256 + threadIdx.x;
  if (i >= N * 32) return;
  int c4 = i & 31;
  float4 v = ((const float4*)y)[i];
  float4 sc = ((const float4*)scale)[c4];
  float4 sh = ((const float4*)shift)[c4];
  v.x = v.x * sc.x + sh.x;
  v.y = v.y * sc.y + sh.y;
  v.z = v.z * sc.z + sh.z;
  v.w = v.w * sc.w + sh.w;
  ((float4*)h)[i] = v;
}

// graph pooling: graph_ids sorted -> one block per graph, binary-searched range
__global__ __launch_bounds__(256) void k_poolg(const float* __restrict__ h,
                                               const int* __restrict__ gid,
                                               float* __restrict__ out, int N) {
  int g = blockIdx.x;
  int lo = 0, hi = N;
  while (lo < hi) { int m = (lo + hi) >> 1; if (gid[m] < g) lo = m + 1; else hi = m; }
  int beg = lo;
  hi = N;
  while (lo < hi) { int m = (lo + hi) >> 1; if (gid[m] <= g) lo = m + 1; else hi = m; }
  int end = lo;
  int t = threadIdx.x;
  int col = t & 127, half = t >> 7;
  float acc = 0.f;
  for (int r = beg + half; r < end; r += 2) acc += h[(size_t)r * D128 + col];
  __shared__ float ls[256];
  ls[t] = acc;
  __syncthreads();
  if (t < 128) {
    float v = ls[t] + ls[t + 128];
    out[(size_t)g * D128 + t] = v / fmaxf((float)(end - beg), 1.f);
  }
}

__global__ void k_poolm(const float* __restrict__ h, const int* __restrict__ mid,
                        float* __restrict__ macc, int* __restrict__ cntm, int N) {
  int i = blockIdx.x * 256 + threadIdx.x;
  if (i >= N * 32) return;
  int n = i >> 5, c4 = i & 31;
  float4 v = ((const float4*)h)[i];
  int m = mid[n];
  float* p = macc + (size_t)m * D128 + c4 * 4;
  atomicAdd(p + 0, v.x);
  atomicAdd(p + 1, v.y);
  atomicAdd(p + 2, v.z);
  atomicAdd(p + 3, v.w);
  if (c4 == 0) atomicAdd(&cntm[m], 1);
}

__global__ void k_divm(const float* __restrict__ macc, const int* __restrict__ cntm,
                       float* __restrict__ hsub, int M) {
  int i = blockIdx.x * 256 + threadIdx.x;
  if (i >= M * 32) return;
  int r = i >> 5, c4 = i & 31;
  float c = fmaxf((float)cntm[r + 1], 1.f);
  float4 v = ((const float4*)(macc + (size_t)(r + 1) * D128))[c4];
  v.x /= c; v.y /= c; v.z /= c; v.w /= c;
  ((float4*)hsub)[i] = v;
}

// small dense: out[r][j] = act(sum_k X[r][k]*W[k][j] + b[j]); 8 rows/block
__global__ __launch_bounds__(256) void k_gemm(const float* __restrict__ X,
                                              const float* __restrict__ W,
                                              const float* __restrict__ b,
                                              float* __restrict__ out,
                                              int Mrows, int K, int Ncols, int relu) {
  __shared__ float xs[8][256];
  int t = threadIdx.x;
  int r0 = blockIdx.x * 8;
  for (int i = t; i < 8 * K; i += 256) {
    int r = i / K, k = i - r * K;
    int gr = r0 + r;
    xs[r][k] = (gr < Mrows) ? X[(size_t)gr * K + k] : 0.f;
  }
  __syncthreads();
  int j = t;
  if (j >= Ncols) return;
  float acc[8] = {};
  for (int k = 0; k < K; ++k) {
    float w = W[(size_t)k * Ncols + j];
#pragma unroll
    for (int r = 0; r < 8; ++r) acc[r] += xs[r][k] * w;
  }
  float bb = b[j];
#pragma unroll
  for (int r = 0; r < 8; ++r) {
    int gr = r0 + r;
    if (gr < Mrows) {
      float v = acc[r] + bb;
      if (relu) v = fmaxf(v, 0.f);
      out[(size_t)gr * Ncols + j] = v;
    }
  }
}

extern "C" void kernel_launch(void* const* d_in, const int* in_sizes, int n_in,
                              void* d_out, int out_size, void* d_ws, size_t ws_size,
                              hipStream_t stream) {
  (void)n_in; (void)out_size; (void)ws_size;
  const float* nf   = (const float*)d_in[0];
  const int*   src  = (const int*)d_in[1];
  const int*   dst  = (const int*)d_in[2];
  const int*   gid  = (const int*)d_in[3];
  const int*   mid  = (const int*)d_in[4];
  const float* Wg   = (const float*)d_in[5];
  const float* bg   = (const float*)d_in[6];
  const float* Wr   = (const float*)d_in[7];
  const float* br   = (const float*)d_in[8];
  const float* gam  = (const float*)d_in[9];
  const float* bet  = (const float*)d_in[10];
  const float* Wf   = (const float*)d_in[11];
  const float* bf   = (const float*)d_in[12];
  const float* W1   = (const float*)d_in[13];
  const float* b1   = (const float*)d_in[14];
  const float* W2   = (const float*)d_in[15];
  const float* b2   = (const float*)d_in[16];

  const int N = in_sizes[0] / D128;
  const int E = in_sizes[1];
  const int G = 512;
  const int M = 2048;

  char* ws = (char*)d_ws;
  size_t off = 0;
  auto alloc = [&](size_t bytes) -> void* {
    void* p = ws + off;
    off = (off + bytes + 255) & ~(size_t)255;
    return p;
  };
  float* h    = (float*)alloc((size_t)N * D128 * 4);
  float* hw   = (float*)alloc((size_t)N * D128 * 4);
  float* yres = (float*)alloc((size_t)N * D128 * 4);
  int*   dego = (int*)alloc((size_t)N * 4);
  int*   degi = (int*)alloc((size_t)N * 4);
  float* ns   = (float*)alloc((size_t)N * 4);
  float* nd   = (float*)alloc((size_t)N * 4);
  int*   rp   = (int*)alloc((size_t)(N + 1) * 4);
  int*   cur  = (int*)alloc((size_t)N * 4);
  int*   csrc = (int*)alloc((size_t)E * 4);
  float* s12  = (float*)alloc(256 * 4);
  float* scsh = (float*)alloc(256 * 4);
  float* macc = (float*)alloc((size_t)(M + 1) * D128 * 4);
  int*   cntm = (int*)alloc((size_t)(M + 1) * 4);
  float* hsub = (float*)alloc((size_t)M * D128 * 4);
  float* fbuf = (float*)alloc((size_t)2048 * 256 * 4);
  float* zbuf = (float*)alloc((size_t)2048 * 256 * 4);

  float* outg  = (float*)d_out;        // graph_feats [512,128]
  float* outgl = outg + (size_t)G * D128;   // out_global  [512,128]
  float* outsb = outgl + (size_t)G * D128;  // out_sub     [2048,128]

  hipMemsetAsync(dego, 0, (size_t)N * 4, stream);
  hipMemsetAsync(degi, 0, (size_t)N * 4, stream);
  hipMemsetAsync(cur,  0, (size_t)N * 4, stream);

  k_deg<<<(E + 255) / 256, 256, 0, stream>>>(src, dst, dego, degi, E);
  k_norm<<<(N + 255) / 256, 256, 0, stream>>>(dego, degi, ns, nd, N);
  k_scan<<<1, 1024, 0, stream>>>(degi, rp, N);
  k_csr<<<(E + 255) / 256, 256, 0, stream>>>(src, dst, rp, cur, csrc, E);

  const float* hin = nf;
  for (int l = 0; l < 3; ++l) {
    k_dualgemm<<<(N + 31) / 32, 256, 0, stream>>>(hin, Wg + l * 16384, Wr + l * 16384,
                                                  br + l * D128, ns, hw, yres, N);
    k_agg<<<(N + 3) / 4, 256, 0, stream>>>(hw, rp, csrc, nd, bg + l * D128, yres, N);
    hipMemsetAsync(s12, 0, 256 * 4, stream);
    k_stats<<<256, 256, 0, stream>>>(yres, s12, s12 + 128, N);
    k_bnfin<<<1, 128, 0, stream>>>(s12, s12 + 128, gam + l * D128, bet + l * D128,
                                   scsh, scsh + 128, 1.f / (float)N);
    k_bnapply<<<((size_t)N * 32 + 255) / 256, 256, 0, stream>>>(yres, scsh, scsh + 128, h, N);
    hin = h;
  }

  k_poolg<<<G, 256, 0, stream>>>(h, gid, outg, N);

  hipMemsetAsync(macc, 0, (size_t)(M + 1) * D128 * 4, stream);
  hipMemsetAsync(cntm, 0, (size_t)(M + 1) * 4, stream);
  k_poolm<<<((size_t)N * 32 + 255) / 256, 256, 0, stream>>>(h, mid, macc, cntm, N);
  k_divm<<<((size_t)M * 32 + 255) / 256, 256, 0, stream>>>(macc, cntm, hsub, M);

  // heads: graph_feats -> out_global ; h_sub -> out_sub
  k_gemm<<<(G + 7) / 8, 256, 0, stream>>>(outg, Wf, bf, fbuf, G, 128, 256, 0);
  k_gemm<<<(G + 7) / 8, 256, 0, stream>>>(fbuf, W1, b1, zbuf, G, 256, 256, 1);
  k_gemm<<<(G + 7) / 8, 256, 0, stream>>>(zbuf, W2, b2, outgl, G, 256, 128, 0);
  k_gemm<<<(M + 7) / 8, 256, 0, stream>>>(hsub, Wf, bf, fbuf, M, 128, 256, 0);
  k_gemm<<<(M + 7) / 8, 256, 0, stream>>>(fbuf, W1, b1, zbuf, M, 256, 256, 1);
  k_gemm<<<(M + 7) / 8, 256, 0, stream>>>(zbuf, W2, b2, outsb, M, 256, 128, 0);
}

// Round 2
// 960.334 us; speedup vs baseline: 1.2067x; 1.2067x over previous
//
#include <hip/hip_runtime.h>

// ---------------------------------------------------------------------------
// GCN forward: 3x (dual GEMM -> edge gather-agg -> BN) -> pooled readouts -> MLP head
// All f32. CSR (by dst) built on-device each launch; gather aggregation (no hot atomics).
// Round 1: heads batched (G+M rows concatenated), proper 64x64 tiled GEMM.
// ---------------------------------------------------------------------------

#define D128 128

__global__ void k_deg(const int* __restrict__ src, const int* __restrict__ dst,
                      int* __restrict__ dego, int* __restrict__ degi, int E) {
  int e = blockIdx.x * 256 + threadIdx.x;
  if (e < E) {
    atomicAdd(&dego[src[e]], 1);
    atomicAdd(&degi[dst[e]], 1);
  }
}

__global__ void k_norm(const int* __restrict__ dego, const int* __restrict__ degi,
                       float* __restrict__ ns, float* __restrict__ nd, int N) {
  int i = blockIdx.x * 256 + threadIdx.x;
  if (i < N) {
    ns[i] = rsqrtf(fmaxf((float)dego[i], 1.f));
    nd[i] = rsqrtf(fmaxf((float)degi[i], 1.f));
  }
}

// exclusive scan of degi -> rp[0..N], single block
__global__ __launch_bounds__(1024) void k_scan(const int* __restrict__ deg,
                                               int* __restrict__ rp, int N) {
  __shared__ int part[1024];
  int t = threadIdx.x;
  int chunk = (N + 1023) >> 10;
  int b = t * chunk;
  int e = min(b + chunk, N);
  int s = 0;
  for (int i = b; i < e; ++i) s += deg[i];
  part[t] = s;
  __syncthreads();
  for (int off = 1; off < 1024; off <<= 1) {
    int v = (t >= off) ? part[t - off] : 0;
    __syncthreads();
    part[t] += v;
    __syncthreads();
  }
  int run = (t == 0) ? 0 : part[t - 1];
  for (int i = b; i < e; ++i) { rp[i] = run; run += deg[i]; }
  if (t == 1023) rp[N] = run;
}

__global__ void k_csr(const int* __restrict__ src, const int* __restrict__ dst,
                      const int* __restrict__ rp, int* __restrict__ cur,
                      int* __restrict__ csrc, int E) {
  int e = blockIdx.x * 256 + threadIdx.x;
  if (e < E) {
    int d = dst[e];
    int p = atomicAdd(&cur[d], 1);
    csrc[rp[d] + p] = src[e];
  }
}

// hw = (h @ Wg) * norm_src (row scale), res = relu(h @ Wr + br)
// block 256 threads, 32 rows/block; thread: 4 rows x 4 cols x 2 matrices
__global__ __launch_bounds__(256) void k_dualgemm(
    const float* __restrict__ h, const float* __restrict__ Wg,
    const float* __restrict__ Wr, const float* __restrict__ brl,
    const float* __restrict__ ns, float* __restrict__ hw,
    float* __restrict__ res, int N) {
  __shared__ float4 hs[32][32];  // 32 rows x 128 floats
  int t = threadIdx.x;
  int row0 = blockIdx.x * 32;
  for (int i = t; i < 1024; i += 256) {
    int r = i >> 5, c = i & 31;
    int gr = row0 + r;
    float4 v = make_float4(0.f, 0.f, 0.f, 0.f);
    if (gr < N) v = ((const float4*)h)[(size_t)gr * 32 + c];
    hs[r][c] = v;
  }
  __syncthreads();
  const int rb = (t >> 5) * 4;
  const int j0 = (t & 31) * 4;
  float accg[4][4] = {};
  float accr[4][4] = {};
  for (int k4 = 0; k4 < 32; ++k4) {
    float a[4][4];
#pragma unroll
    for (int r = 0; r < 4; ++r) {
      float4 v = hs[rb + r][k4];
      a[r][0] = v.x; a[r][1] = v.y; a[r][2] = v.z; a[r][3] = v.w;
    }
#pragma unroll
    for (int kk = 0; kk < 4; ++kk) {
      int k = k4 * 4 + kk;
      float4 wg = *(const float4*)(Wg + k * D128 + j0);
      float4 wr = *(const float4*)(Wr + k * D128 + j0);
      float wga[4] = {wg.x, wg.y, wg.z, wg.w};
      float wra[4] = {wr.x, wr.y, wr.z, wr.w};
#pragma unroll
      for (int r = 0; r < 4; ++r) {
#pragma unroll
        for (int j = 0; j < 4; ++j) {
          accg[r][j] += a[r][kk] * wga[j];
          accr[r][j] += a[r][kk] * wra[j];
        }
      }
    }
  }
  float4 bb = *(const float4*)(brl + j0);
  float ba[4] = {bb.x, bb.y, bb.z, bb.w};
#pragma unroll
  for (int r = 0; r < 4; ++r) {
    int gr = row0 + rb + r;
    if (gr >= N) continue;
    float s = ns[gr];
    float4 og, orr;
    og.x = accg[r][0] * s; og.y = accg[r][1] * s;
    og.z = accg[r][2] * s; og.w = accg[r][3] * s;
    orr.x = fmaxf(accr[r][0] + ba[0], 0.f);
    orr.y = fmaxf(accr[r][1] + ba[1], 0.f);
    orr.z = fmaxf(accr[r][2] + ba[2], 0.f);
    orr.w = fmaxf(accr[r][3] + ba[3], 0.f);
    *(float4*)(hw + (size_t)gr * D128 + j0) = og;
    *(float4*)(res + (size_t)gr * D128 + j0) = orr;
  }
}

// one wave per node: y = relu(agg*nd + bg) + res, written over res (yres)
__global__ __launch_bounds__(256) void k_agg(
    const float* __restrict__ hw, const int* __restrict__ rp,
    const int* __restrict__ csrc, const float* __restrict__ nd,
    const float* __restrict__ bgl, float* __restrict__ yres, int N) {
  int n = blockIdx.x * 4 + (threadIdx.x >> 6);
  int lane = threadIdx.x & 63;
  if (n >= N) return;
  int beg = rp[n], end = rp[n + 1];
  float ax = 0.f, ay = 0.f;
  for (int e = beg; e < end; ++e) {
    int s = csrc[e];
    float2 v = ((const float2*)hw)[(size_t)s * 64 + lane];
    ax += v.x; ay += v.y;
  }
  float ndv = nd[n];
  float2 b = ((const float2*)bgl)[lane];
  float2 r = ((const float2*)yres)[(size_t)n * 64 + lane];
  float2 y;
  y.x = fmaxf(ax * ndv + b.x, 0.f) + r.x;
  y.y = fmaxf(ay * ndv + b.y, 0.f) + r.y;
  ((float2*)yres)[(size_t)n * 64 + lane] = y;
}

__global__ __launch_bounds__(256) void k_stats(const float* __restrict__ y,
                                               float* __restrict__ s1,
                                               float* __restrict__ s2, int N) {
  int t = threadIdx.x;
  int col = t & 127, half = t >> 7;
  float a = 0.f, q = 0.f;
  for (int r = blockIdx.x * 2 + half; r < N; r += gridDim.x * 2) {
    float v = y[(size_t)r * D128 + col];
    a += v; q += v * v;
  }
  __shared__ float ls[256], lq[256];
  ls[t] = a; lq[t] = q;
  __syncthreads();
  if (t < 128) {
    atomicAdd(&s1[col], ls[t] + ls[t + 128]);
    atomicAdd(&s2[col], lq[t] + lq[t + 128]);
  }
}

__global__ void k_bnfin(const float* __restrict__ s1, const float* __restrict__ s2,
                        const float* __restrict__ gam, const float* __restrict__ bet,
                        float* __restrict__ scale, float* __restrict__ shift, float invN) {
  int j = threadIdx.x;
  float mu = s1[j] * invN;
  float var = s2[j] * invN - mu * mu;
  float sc = gam[j] * rsqrtf(var + 1e-5f);
  scale[j] = sc;
  shift[j] = bet[j] - mu * sc;
}

__global__ void k_bnapply(const float* __restrict__ y, const float* __restrict__ scale,
                          const float* __restrict__ shift, float* __restrict__ h, int N) {
  int i = blockIdx.x * 256 + threadIdx.x;
  if (i >= N * 32) return;
  int c4 = i & 31;
  float4 v = ((const float4*)y)[i];
  float4 sc = ((const float4*)scale)[c4];
  float4 sh = ((const float4*)shift)[c4];
  v.x = v.x * sc.x + sh.x;
  v.y = v.y * sc.y + sh.y;
  v.z = v.z * sc.z + sh.z;
  v.w = v.w * sc.w + sh.w;
  ((float4*)h)[i] = v;
}

// graph pooling: graph_ids sorted -> one block per graph, binary-searched range
// writes mean row to BOTH d_out (graph_feats) and xcat row g (head input)
__global__ __launch_bounds__(256) void k_poolg(const float* __restrict__ h,
                                               const int* __restrict__ gid,
                                               float* __restrict__ out,
                                               float* __restrict__ xcat, int N) {
  int g = blockIdx.x;
  int lo = 0, hi = N;
  while (lo < hi) { int m = (lo + hi) >> 1; if (gid[m] < g) lo = m + 1; else hi = m; }
  int beg = lo;
  hi = N;
  while (lo < hi) { int m = (lo + hi) >> 1; if (gid[m] <= g) lo = m + 1; else hi = m; }
  int end = lo;
  int t = threadIdx.x;
  int col = t & 127, half = t >> 7;
  float acc = 0.f;
  for (int r = beg + half; r < end; r += 2) acc += h[(size_t)r * D128 + col];
  __shared__ float ls[256];
  ls[t] = acc;
  __syncthreads();
  if (t < 128) {
    float v = ls[t] + ls[t + 128];
    v = v / fmaxf((float)(end - beg), 1.f);
    out[(size_t)g * D128 + t] = v;
    xcat[(size_t)g * D128 + t] = v;
  }
}

__global__ void k_poolm(const float* __restrict__ h, const int* __restrict__ mid,
                        float* __restrict__ macc, int* __restrict__ cntm, int N) {
  int i = blockIdx.x * 256 + threadIdx.x;
  if (i >= N * 32) return;
  int n = i >> 5, c4 = i & 31;
  float4 v = ((const float4*)h)[i];
  int m = mid[n];
  float* p = macc + (size_t)m * D128 + c4 * 4;
  atomicAdd(p + 0, v.x);
  atomicAdd(p + 1, v.y);
  atomicAdd(p + 2, v.z);
  atomicAdd(p + 3, v.w);
  if (c4 == 0) atomicAdd(&cntm[m], 1);
}

// divide motif sums, write into xcat rows [512 .. 512+M)
__global__ void k_divm(const float* __restrict__ macc, const int* __restrict__ cntm,
                       float* __restrict__ hsub, int M) {
  int i = blockIdx.x * 256 + threadIdx.x;
  if (i >= M * 32) return;
  int r = i >> 5, c4 = i & 31;
  float c = fmaxf((float)cntm[r + 1], 1.f);
  float4 v = ((const float4*)(macc + (size_t)(r + 1) * D128))[c4];
  v.x /= c; v.y /= c; v.z /= c; v.w /= c;
  ((float4*)hsub)[i] = v;
}

// tiled GEMM: out = act(X[M,K] @ W[K,N] + b), BM=64 BN=64 BK=32, 256 thr, 4x4/thr
__global__ __launch_bounds__(256) void k_gemm64(
    const float* __restrict__ X, const float* __restrict__ W,
    const float* __restrict__ b, float* __restrict__ out,
    int Mrows, int K, int Ncols, int relu) {
  __shared__ float xs[64][33];
  __shared__ float ws[32][68];
  int t = threadIdx.x;
  int row0 = blockIdx.x * 64, col0 = blockIdx.y * 64;
  int tx = t & 15, ty = t >> 4;
  int j0 = tx * 4, r0 = ty * 4;
  float acc[4][4] = {};
  for (int k0 = 0; k0 < K; k0 += 32) {
    for (int i = t; i < 512; i += 256) {
      int r = i >> 3, c4 = i & 7;
      int gr = row0 + r;
      float4 v = make_float4(0.f, 0.f, 0.f, 0.f);
      if (gr < Mrows) v = *(const float4*)(X + (size_t)gr * K + k0 + c4 * 4);
      xs[r][c4 * 4 + 0] = v.x; xs[r][c4 * 4 + 1] = v.y;
      xs[r][c4 * 4 + 2] = v.z; xs[r][c4 * 4 + 3] = v.w;
    }
    for (int i = t; i < 512; i += 256) {
      int r = i >> 4, c4 = i & 15;
      float4 v = *(const float4*)(W + (size_t)(k0 + r) * Ncols + col0 + c4 * 4);
      *(float4*)(&ws[r][c4 * 4]) = v;
    }
    __syncthreads();
#pragma unroll
    for (int kk = 0; kk < 32; ++kk) {
      float a_[4];
#pragma unroll
      for (int r = 0; r < 4; ++r) a_[r] = xs[r0 + r][kk];
      float4 wv = *(const float4*)(&ws[kk][j0]);
      float b_[4] = {wv.x, wv.y, wv.z, wv.w};
#pragma unroll
      for (int r = 0; r < 4; ++r)
#pragma unroll
        for (int j = 0; j < 4; ++j) acc[r][j] += a_[r] * b_[j];
    }
    __syncthreads();
  }
  float4 bb = *(const float4*)(b + col0 + j0);
  float ba[4] = {bb.x, bb.y, bb.z, bb.w};
#pragma unroll
  for (int r = 0; r < 4; ++r) {
    int gr = row0 + r0 + r;
    if (gr >= Mrows) continue;
    float4 o;
    o.x = acc[r][0] + ba[0]; o.y = acc[r][1] + ba[1];
    o.z = acc[r][2] + ba[2]; o.w = acc[r][3] + ba[3];
    if (relu) {
      o.x = fmaxf(o.x, 0.f); o.y = fmaxf(o.y, 0.f);
      o.z = fmaxf(o.z, 0.f); o.w = fmaxf(o.w, 0.f);
    }
    *(float4*)(out + (size_t)gr * Ncols + col0 + j0) = o;
  }
}

extern "C" void kernel_launch(void* const* d_in, const int* in_sizes, int n_in,
                              void* d_out, int out_size, void* d_ws, size_t ws_size,
                              hipStream_t stream) {
  (void)n_in; (void)out_size; (void)ws_size;
  const float* nf   = (const float*)d_in[0];
  const int*   src  = (const int*)d_in[1];
  const int*   dst  = (const int*)d_in[2];
  const int*   gid  = (const int*)d_in[3];
  const int*   mid  = (const int*)d_in[4];
  const float* Wg   = (const float*)d_in[5];
  const float* bg   = (const float*)d_in[6];
  const float* Wr   = (const float*)d_in[7];
  const float* br   = (const float*)d_in[8];
  const float* gam  = (const float*)d_in[9];
  const float* bet  = (const float*)d_in[10];
  const float* Wf   = (const float*)d_in[11];
  const float* bf   = (const float*)d_in[12];
  const float* W1   = (const float*)d_in[13];
  const float* b1   = (const float*)d_in[14];
  const float* W2   = (const float*)d_in[15];
  const float* b2   = (const float*)d_in[16];

  const int N = in_sizes[0] / D128;
  const int E = in_sizes[1];
  const int G = 512;
  const int M = 2048;
  const int R = G + M;  // 2560 batched head rows

  char* ws = (char*)d_ws;
  size_t off = 0;
  auto alloc = [&](size_t bytes) -> void* {
    void* p = ws + off;
    off = (off + bytes + 255) & ~(size_t)255;
    return p;
  };
  float* h    = (float*)alloc((size_t)N * D128 * 4);
  float* hw   = (float*)alloc((size_t)N * D128 * 4);
  float* yres = (float*)alloc((size_t)N * D128 * 4);
  int*   dego = (int*)alloc((size_t)N * 4);
  int*   degi = (int*)alloc((size_t)N * 4);
  float* ns   = (float*)alloc((size_t)N * 4);
  float* nd   = (float*)alloc((size_t)N * 4);
  int*   rp   = (int*)alloc((size_t)(N + 1) * 4);
  int*   cur  = (int*)alloc((size_t)N * 4);
  int*   csrc = (int*)alloc((size_t)E * 4);
  float* s12  = (float*)alloc(256 * 4);
  float* scsh = (float*)alloc(256 * 4);
  float* macc = (float*)alloc((size_t)(M + 1) * D128 * 4);
  int*   cntm = (int*)alloc((size_t)(M + 1) * 4);
  float* xcat = (float*)alloc((size_t)R * D128 * 4);
  float* fbuf = (float*)alloc((size_t)R * 256 * 4);
  float* zbuf = (float*)alloc((size_t)R * 256 * 4);

  float* outg  = (float*)d_out;             // graph_feats [512,128]
  float* outgl = outg + (size_t)G * D128;   // out_global [512,128] (followed by out_sub [2048,128], contiguous)

  hipMemsetAsync(dego, 0, (size_t)N * 4, stream);
  hipMemsetAsync(degi, 0, (size_t)N * 4, stream);
  hipMemsetAsync(cur,  0, (size_t)N * 4, stream);

  k_deg<<<(E + 255) / 256, 256, 0, stream>>>(src, dst, dego, degi, E);
  k_norm<<<(N + 255) / 256, 256, 0, stream>>>(dego, degi, ns, nd, N);
  k_scan<<<1, 1024, 0, stream>>>(degi, rp, N);
  k_csr<<<(E + 255) / 256, 256, 0, stream>>>(src, dst, rp, cur, csrc, E);

  const float* hin = nf;
  for (int l = 0; l < 3; ++l) {
    k_dualgemm<<<(N + 31) / 32, 256, 0, stream>>>(hin, Wg + l * 16384, Wr + l * 16384,
                                                  br + l * D128, ns, hw, yres, N);
    k_agg<<<(N + 3) / 4, 256, 0, stream>>>(hw, rp, csrc, nd, bg + l * D128, yres, N);
    hipMemsetAsync(s12, 0, 256 * 4, stream);
    k_stats<<<256, 256, 0, stream>>>(yres, s12, s12 + 128, N);
    k_bnfin<<<1, 128, 0, stream>>>(s12, s12 + 128, gam + l * D128, bet + l * D128,
                                   scsh, scsh + 128, 1.f / (float)N);
    k_bnapply<<<((size_t)N * 32 + 255) / 256, 256, 0, stream>>>(yres, scsh, scsh + 128, h, N);
    hin = h;
  }

  k_poolg<<<G, 256, 0, stream>>>(h, gid, outg, xcat, N);

  hipMemsetAsync(macc, 0, (size_t)(M + 1) * D128 * 4, stream);
  hipMemsetAsync(cntm, 0, (size_t)(M + 1) * 4, stream);
  k_poolm<<<((size_t)N * 32 + 255) / 256, 256, 0, stream>>>(h, mid, macc, cntm, N);
  k_divm<<<((size_t)M * 32 + 255) / 256, 256, 0, stream>>>(macc, cntm, xcat + (size_t)G * D128, M);

  // batched head on xcat [2560,128]: 3 GEMMs; final writes d_out directly
  // (out_global then out_sub are contiguous in d_out)
  dim3 g1((R + 63) / 64, 256 / 64);
  k_gemm64<<<g1, 256, 0, stream>>>(xcat, Wf, bf, fbuf, R, 128, 256, 0);
  dim3 g2((R + 63) / 64, 256 / 64);
  k_gemm64<<<g2, 256, 0, stream>>>(fbuf, W1, b1, zbuf, R, 256, 256, 1);
  dim3 g3((R + 63) / 64, 128 / 64);
  k_gemm64<<<g3, 256, 0, stream>>>(zbuf, W2, b2, outgl, R, 256, 128, 0);
}

// Round 3
// 873.407 us; speedup vs baseline: 1.3268x; 1.0995x over previous
//
#include <hip/hip_runtime.h>

// ---------------------------------------------------------------------------
// GCN forward: 3x (dual GEMM -> edge gather-agg -> BN-fused) -> CSR pooled
// readouts -> batched MLP head. All f32.
// Round 2: motif pooling via CSR gather (no atomics); BN apply fused into
// consumers (affine commutes with mean).
// ---------------------------------------------------------------------------

#define D128 128

__global__ void k_deg(const int* __restrict__ src, const int* __restrict__ dst,
                      int* __restrict__ dego, int* __restrict__ degi, int E) {
  int e = blockIdx.x * 256 + threadIdx.x;
  if (e < E) {
    atomicAdd(&dego[src[e]], 1);
    atomicAdd(&degi[dst[e]], 1);
  }
}

__global__ void k_hist_m(const int* __restrict__ mid, int* __restrict__ cntm, int N) {
  int i = blockIdx.x * 256 + threadIdx.x;
  if (i < N) atomicAdd(&cntm[mid[i]], 1);
}

__global__ void k_norm(const int* __restrict__ dego, const int* __restrict__ degi,
                       float* __restrict__ ns, float* __restrict__ nd, int N) {
  int i = blockIdx.x * 256 + threadIdx.x;
  if (i < N) {
    ns[i] = rsqrtf(fmaxf((float)dego[i], 1.f));
    nd[i] = rsqrtf(fmaxf((float)degi[i], 1.f));
  }
}

// exclusive scan of deg[0..N) -> rp[0..N], single block
__global__ __launch_bounds__(1024) void k_scan(const int* __restrict__ deg,
                                               int* __restrict__ rp, int N) {
  __shared__ int part[1024];
  int t = threadIdx.x;
  int chunk = (N + 1023) >> 10;
  int b = t * chunk;
  int e = min(b + chunk, N);
  int s = 0;
  for (int i = b; i < e; ++i) s += deg[i];
  part[t] = s;
  __syncthreads();
  for (int off = 1; off < 1024; off <<= 1) {
    int v = (t >= off) ? part[t - off] : 0;
    __syncthreads();
    part[t] += v;
    __syncthreads();
  }
  int run = (t == 0) ? 0 : part[t - 1];
  for (int i = b; i < e; ++i) { rp[i] = run; run += deg[i]; }
  if (t == 1023) rp[N] = run;
}

__global__ void k_csr(const int* __restrict__ src, const int* __restrict__ dst,
                      const int* __restrict__ rp, int* __restrict__ cur,
                      int* __restrict__ csrc, int E) {
  int e = blockIdx.x * 256 + threadIdx.x;
  if (e < E) {
    int d = dst[e];
    int p = atomicAdd(&cur[d], 1);
    csrc[rp[d] + p] = src[e];
  }
}

__global__ void k_mcsr(const int* __restrict__ mid, const int* __restrict__ mrp,
                       int* __restrict__ cur, int* __restrict__ mlist, int N) {
  int n = blockIdx.x * 256 + threadIdx.x;
  if (n < N) {
    int m = mid[n];
    int p = atomicAdd(&cur[m], 1);
    mlist[mrp[m] + p] = n;
  }
}

// hw = (hn @ Wg) * norm_src, res = relu(hn @ Wr + br), hn = h*scale+shift (opt)
// block 256 threads, 32 rows/block; thread: 4 rows x 4 cols x 2 matrices
__global__ __launch_bounds__(256) void k_dualgemm(
    const float* __restrict__ h, const float* __restrict__ Wg,
    const float* __restrict__ Wr, const float* __restrict__ brl,
    const float* __restrict__ ns, const float* __restrict__ scale,
    const float* __restrict__ shift, float* __restrict__ hw,
    float* __restrict__ res, int N) {
  __shared__ float4 hs[32][32];  // 32 rows x 128 floats
  int t = threadIdx.x;
  int row0 = blockIdx.x * 32;
  for (int i = t; i < 1024; i += 256) {
    int r = i >> 5, c = i & 31;
    int gr = row0 + r;
    float4 v = make_float4(0.f, 0.f, 0.f, 0.f);
    if (gr < N) {
      v = ((const float4*)h)[(size_t)gr * 32 + c];
      if (scale) {
        float4 sc = ((const float4*)scale)[c];
        float4 sh = ((const float4*)shift)[c];
        v.x = v.x * sc.x + sh.x;
        v.y = v.y * sc.y + sh.y;
        v.z = v.z * sc.z + sh.z;
        v.w = v.w * sc.w + sh.w;
      }
    }
    hs[r][c] = v;
  }
  __syncthreads();
  const int rb = (t >> 5) * 4;
  const int j0 = (t & 31) * 4;
  float accg[4][4] = {};
  float accr[4][4] = {};
  for (int k4 = 0; k4 < 32; ++k4) {
    float a[4][4];
#pragma unroll
    for (int r = 0; r < 4; ++r) {
      float4 v = hs[rb + r][k4];
      a[r][0] = v.x; a[r][1] = v.y; a[r][2] = v.z; a[r][3] = v.w;
    }
#pragma unroll
    for (int kk = 0; kk < 4; ++kk) {
      int k = k4 * 4 + kk;
      float4 wg = *(const float4*)(Wg + k * D128 + j0);
      float4 wr = *(const float4*)(Wr + k * D128 + j0);
      float wga[4] = {wg.x, wg.y, wg.z, wg.w};
      float wra[4] = {wr.x, wr.y, wr.z, wr.w};
#pragma unroll
      for (int r = 0; r < 4; ++r) {
#pragma unroll
        for (int j = 0; j < 4; ++j) {
          accg[r][j] += a[r][kk] * wga[j];
          accr[r][j] += a[r][kk] * wra[j];
        }
      }
    }
  }
  float4 bb = *(const float4*)(brl + j0);
  float ba[4] = {bb.x, bb.y, bb.z, bb.w};
#pragma unroll
  for (int r = 0; r < 4; ++r) {
    int gr = row0 + rb + r;
    if (gr >= N) continue;
    float s = ns[gr];
    float4 og, orr;
    og.x = accg[r][0] * s; og.y = accg[r][1] * s;
    og.z = accg[r][2] * s; og.w = accg[r][3] * s;
    orr.x = fmaxf(accr[r][0] + ba[0], 0.f);
    orr.y = fmaxf(accr[r][1] + ba[1], 0.f);
    orr.z = fmaxf(accr[r][2] + ba[2], 0.f);
    orr.w = fmaxf(accr[r][3] + ba[3], 0.f);
    *(float4*)(hw + (size_t)gr * D128 + j0) = og;
    *(float4*)(res + (size_t)gr * D128 + j0) = orr;
  }
}

// one wave per node: y = relu(agg*nd + bg) + res, written over res (yres)
__global__ __launch_bounds__(256) void k_agg(
    const float* __restrict__ hw, const int* __restrict__ rp,
    const int* __restrict__ csrc, const float* __restrict__ nd,
    const float* __restrict__ bgl, float* __restrict__ yres, int N) {
  int n = blockIdx.x * 4 + (threadIdx.x >> 6);
  int lane = threadIdx.x & 63;
  if (n >= N) return;
  int beg = rp[n], end = rp[n + 1];
  float ax = 0.f, ay = 0.f;
  for (int e = beg; e < end; ++e) {
    int s = csrc[e];
    float2 v = ((const float2*)hw)[(size_t)s * 64 + lane];
    ax += v.x; ay += v.y;
  }
  float ndv = nd[n];
  float2 b = ((const float2*)bgl)[lane];
  float2 r = ((const float2*)yres)[(size_t)n * 64 + lane];
  float2 y;
  y.x = fmaxf(ax * ndv + b.x, 0.f) + r.x;
  y.y = fmaxf(ay * ndv + b.y, 0.f) + r.y;
  ((float2*)yres)[(size_t)n * 64 + lane] = y;
}

__global__ __launch_bounds__(256) void k_stats(const float* __restrict__ y,
                                               float* __restrict__ s1,
                                               float* __restrict__ s2, int N) {
  int t = threadIdx.x;
  int col = t & 127, half = t >> 7;
  float a = 0.f, q = 0.f;
  for (int r = blockIdx.x * 2 + half; r < N; r += gridDim.x * 2) {
    float v = y[(size_t)r * D128 + col];
    a += v; q += v * v;
  }
  __shared__ float ls[256], lq[256];
  ls[t] = a; lq[t] = q;
  __syncthreads();
  if (t < 128) {
    atomicAdd(&s1[col], ls[t] + ls[t + 128]);
    atomicAdd(&s2[col], lq[t] + lq[t + 128]);
  }
}

__global__ void k_bnfin(const float* __restrict__ s1, const float* __restrict__ s2,
                        const float* __restrict__ gam, const float* __restrict__ bet,
                        float* __restrict__ scale, float* __restrict__ shift, float invN) {
  int j = threadIdx.x;
  float mu = s1[j] * invN;
  float var = s2[j] * invN - mu * mu;
  float sc = gam[j] * rsqrtf(var + 1e-5f);
  scale[j] = sc;
  shift[j] = bet[j] - mu * sc;
}

// graph pooling: graph_ids sorted -> one block per graph, binary-searched range
// pools RAW yres, applies BN affine to the mean; writes d_out + xcat
__global__ __launch_bounds__(256) void k_poolg(const float* __restrict__ y,
                                               const int* __restrict__ gid,
                                               const float* __restrict__ scale,
                                               const float* __restrict__ shift,
                                               float* __restrict__ out,
                                               float* __restrict__ xcat, int N) {
  int g = blockIdx.x;
  int lo = 0, hi = N;
  while (lo < hi) { int m = (lo + hi) >> 1; if (gid[m] < g) lo = m + 1; else hi = m; }
  int beg = lo;
  hi = N;
  while (lo < hi) { int m = (lo + hi) >> 1; if (gid[m] <= g) lo = m + 1; else hi = m; }
  int end = lo;
  int t = threadIdx.x;
  int col = t & 127, half = t >> 7;
  float acc = 0.f;
  for (int r = beg + half; r < end; r += 2) acc += y[(size_t)r * D128 + col];
  __shared__ float ls[256];
  ls[t] = acc;
  __syncthreads();
  if (t < 128) {
    float v = ls[t] + ls[t + 128];
    v = v / fmaxf((float)(end - beg), 1.f);
    v = v * scale[t] + shift[t];
    out[(size_t)g * D128 + t] = v;
    xcat[(size_t)g * D128 + t] = v;
  }
}

// motif pooling via CSR gather: one block per motif m in [1..M]
__global__ __launch_bounds__(256) void k_poolmg(const float* __restrict__ y,
                                                const int* __restrict__ mrp,
                                                const int* __restrict__ mlist,
                                                const float* __restrict__ scale,
                                                const float* __restrict__ shift,
                                                float* __restrict__ xsub, int M) {
  int m = blockIdx.x + 1;
  int beg = mrp[m], end = mrp[m + 1];
  int t = threadIdx.x;
  int col = t & 127, half = t >> 7;
  float acc = 0.f;
  for (int r = beg + half; r < end; r += 2) {
    int n = mlist[r];
    acc += y[(size_t)n * D128 + col];
  }
  __shared__ float ls[256];
  ls[t] = acc;
  __syncthreads();
  if (t < 128) {
    float v = ls[t] + ls[t + 128];
    v = v / fmaxf((float)(end - beg), 1.f);
    v = v * scale[t] + shift[t];
    xsub[(size_t)(m - 1) * D128 + t] = v;
  }
}

// tiled GEMM: out = act(X[M,K] @ W[K,N] + b), BM=64 BN=64 BK=32, 256 thr, 4x4/thr
__global__ __launch_bounds__(256) void k_gemm64(
    const float* __restrict__ X, const float* __restrict__ W,
    const float* __restrict__ b, float* __restrict__ out,
    int Mrows, int K, int Ncols, int relu) {
  __shared__ float xs[64][33];
  __shared__ float ws[32][68];
  int t = threadIdx.x;
  int row0 = blockIdx.x * 64, col0 = blockIdx.y * 64;
  int tx = t & 15, ty = t >> 4;
  int j0 = tx * 4, r0 = ty * 4;
  float acc[4][4] = {};
  for (int k0 = 0; k0 < K; k0 += 32) {
    for (int i = t; i < 512; i += 256) {
      int r = i >> 3, c4 = i & 7;
      int gr = row0 + r;
      float4 v = make_float4(0.f, 0.f, 0.f, 0.f);
      if (gr < Mrows) v = *(const float4*)(X + (size_t)gr * K + k0 + c4 * 4);
      xs[r][c4 * 4 + 0] = v.x; xs[r][c4 * 4 + 1] = v.y;
      xs[r][c4 * 4 + 2] = v.z; xs[r][c4 * 4 + 3] = v.w;
    }
    for (int i = t; i < 512; i += 256) {
      int r = i >> 4, c4 = i & 15;
      float4 v = *(const float4*)(W + (size_t)(k0 + r) * Ncols + col0 + c4 * 4);
      *(float4*)(&ws[r][c4 * 4]) = v;
    }
    __syncthreads();
#pragma unroll
    for (int kk = 0; kk < 32; ++kk) {
      float a_[4];
#pragma unroll
      for (int r = 0; r < 4; ++r) a_[r] = xs[r0 + r][kk];
      float4 wv = *(const float4*)(&ws[kk][j0]);
      float b_[4] = {wv.x, wv.y, wv.z, wv.w};
#pragma unroll
      for (int r = 0; r < 4; ++r)
#pragma unroll
        for (int j = 0; j < 4; ++j) acc[r][j] += a_[r] * b_[j];
    }
    __syncthreads();
  }
  float4 bb = *(const float4*)(b + col0 + j0);
  float ba[4] = {bb.x, bb.y, bb.z, bb.w};
#pragma unroll
  for (int r = 0; r < 4; ++r) {
    int gr = row0 + r0 + r;
    if (gr >= Mrows) continue;
    float4 o;
    o.x = acc[r][0] + ba[0]; o.y = acc[r][1] + ba[1];
    o.z = acc[r][2] + ba[2]; o.w = acc[r][3] + ba[3];
    if (relu) {
      o.x = fmaxf(o.x, 0.f); o.y = fmaxf(o.y, 0.f);
      o.z = fmaxf(o.z, 0.f); o.w = fmaxf(o.w, 0.f);
    }
    *(float4*)(out + (size_t)gr * Ncols + col0 + j0) = o;
  }
}

extern "C" void kernel_launch(void* const* d_in, const int* in_sizes, int n_in,
                              void* d_out, int out_size, void* d_ws, size_t ws_size,
                              hipStream_t stream) {
  (void)n_in; (void)out_size; (void)ws_size;
  const float* nf   = (const float*)d_in[0];
  const int*   src  = (const int*)d_in[1];
  const int*   dst  = (const int*)d_in[2];
  const int*   gid  = (const int*)d_in[3];
  const int*   mid  = (const int*)d_in[4];
  const float* Wg   = (const float*)d_in[5];
  const float* bg   = (const float*)d_in[6];
  const float* Wr   = (const float*)d_in[7];
  const float* br   = (const float*)d_in[8];
  const float* gam  = (const float*)d_in[9];
  const float* bet  = (const float*)d_in[10];
  const float* Wf   = (const float*)d_in[11];
  const float* bf   = (const float*)d_in[12];
  const float* W1   = (const float*)d_in[13];
  const float* b1   = (const float*)d_in[14];
  const float* W2   = (const float*)d_in[15];
  const float* b2   = (const float*)d_in[16];

  const int N = in_sizes[0] / D128;
  const int E = in_sizes[1];
  const int G = 512;
  const int M = 2048;
  const int R = G + M;  // 2560 batched head rows

  char* ws = (char*)d_ws;
  size_t off = 0;
  auto alloc = [&](size_t bytes) -> void* {
    void* p = ws + off;
    off = (off + bytes + 255) & ~(size_t)255;
    return p;
  };
  float* hw   = (float*)alloc((size_t)N * D128 * 4);
  float* yres = (float*)alloc((size_t)N * D128 * 4);
  int*   dego = (int*)alloc((size_t)N * 4);
  int*   degi = (int*)alloc((size_t)N * 4);
  float* ns   = (float*)alloc((size_t)N * 4);
  float* nd   = (float*)alloc((size_t)N * 4);
  int*   rp   = (int*)alloc((size_t)(N + 1) * 4);
  int*   cur  = (int*)alloc((size_t)N * 4);
  int*   csrc = (int*)alloc((size_t)E * 4);
  int*   cntm = (int*)alloc((size_t)(M + 1) * 4);
  int*   mrp  = (int*)alloc((size_t)(M + 2) * 4);
  int*   mcur = (int*)alloc((size_t)(M + 1) * 4);
  int*   mlist= (int*)alloc((size_t)N * 4);
  float* s12  = (float*)alloc(256 * 4);
  float* scsh = (float*)alloc(256 * 4);
  float* xcat = (float*)alloc((size_t)R * D128 * 4);
  float* fbuf = (float*)alloc((size_t)R * 256 * 4);
  float* zbuf = (float*)alloc((size_t)R * 256 * 4);

  float* outg  = (float*)d_out;             // graph_feats [512,128]
  float* outgl = outg + (size_t)G * D128;   // out_global [512,128] then out_sub [2048,128]

  hipMemsetAsync(dego, 0, (size_t)N * 4, stream);
  hipMemsetAsync(degi, 0, (size_t)N * 4, stream);
  hipMemsetAsync(cur,  0, (size_t)N * 4, stream);
  hipMemsetAsync(cntm, 0, (size_t)(M + 1) * 4, stream);
  hipMemsetAsync(mcur, 0, (size_t)(M + 1) * 4, stream);

  k_deg<<<(E + 255) / 256, 256, 0, stream>>>(src, dst, dego, degi, E);
  k_hist_m<<<(N + 255) / 256, 256, 0, stream>>>(mid, cntm, N);
  k_norm<<<(N + 255) / 256, 256, 0, stream>>>(dego, degi, ns, nd, N);
  k_scan<<<1, 1024, 0, stream>>>(degi, rp, N);
  k_scan<<<1, 1024, 0, stream>>>(cntm, mrp, M + 1);
  k_csr<<<(E + 255) / 256, 256, 0, stream>>>(src, dst, rp, cur, csrc, E);
  k_mcsr<<<(N + 255) / 256, 256, 0, stream>>>(mid, mrp, mcur, mlist, N);

  const float* hin = nf;
  for (int l = 0; l < 3; ++l) {
    const float* sc = (l == 0) ? nullptr : scsh;
    const float* sh = (l == 0) ? nullptr : (scsh + 128);
    k_dualgemm<<<(N + 31) / 32, 256, 0, stream>>>(hin, Wg + l * 16384, Wr + l * 16384,
                                                  br + l * D128, ns, sc, sh, hw, yres, N);
    k_agg<<<(N + 3) / 4, 256, 0, stream>>>(hw, rp, csrc, nd, bg + l * D128, yres, N);
    hipMemsetAsync(s12, 0, 256 * 4, stream);
    k_stats<<<256, 256, 0, stream>>>(yres, s12, s12 + 128, N);
    k_bnfin<<<1, 128, 0, stream>>>(s12, s12 + 128, gam + l * D128, bet + l * D128,
                                   scsh, scsh + 128, 1.f / (float)N);
    hin = yres;
  }

  // pooled readouts on RAW yres, BN affine applied to the means
  k_poolg<<<G, 256, 0, stream>>>(yres, gid, scsh, scsh + 128, outg, xcat, N);
  k_poolmg<<<M, 256, 0, stream>>>(yres, mrp, mlist, scsh, scsh + 128,
                                  xcat + (size_t)G * D128, M);

  // batched head on xcat [2560,128]: 3 GEMMs; final writes d_out directly
  dim3 g1((R + 63) / 64, 256 / 64);
  k_gemm64<<<g1, 256, 0, stream>>>(xcat, Wf, bf, fbuf, R, 128, 256, 0);
  dim3 g2((R + 63) / 64, 256 / 64);
  k_gemm64<<<g2, 256, 0, stream>>>(fbuf, W1, b1, zbuf, R, 256, 256, 1);
  dim3 g3((R + 63) / 64, 128 / 64);
  k_gemm64<<<g3, 256, 0, stream>>>(zbuf, W2, b2, outgl, R, 256, 128, 0);
}

// Round 4
// 799.942 us; speedup vs baseline: 1.4487x; 1.0918x over previous
//
#include <hip/hip_runtime.h>

// ---------------------------------------------------------------------------
// GCN forward: 3x (dual GEMM -> edge gather-agg -> BN-fused) -> CSR pooled
// readouts -> batched MLP head. All f32.
// Round 3: hierarchical scan (coalesced, full-grid) replaces 77us single-block
// scan; zero-init memsets consolidated into one block.
// ---------------------------------------------------------------------------

#define D128 128

__global__ void k_deg(const int* __restrict__ src, const int* __restrict__ dst,
                      int* __restrict__ dego, int* __restrict__ degi, int E) {
  int e = blockIdx.x * 256 + threadIdx.x;
  if (e < E) {
    atomicAdd(&dego[src[e]], 1);
    atomicAdd(&degi[dst[e]], 1);
  }
}

__global__ void k_hist_m(const int* __restrict__ mid, int* __restrict__ cntm, int N) {
  int i = blockIdx.x * 256 + threadIdx.x;
  if (i < N) atomicAdd(&cntm[mid[i]], 1);
}

__global__ void k_norm(const int* __restrict__ dego, const int* __restrict__ degi,
                       float* __restrict__ ns, float* __restrict__ nd, int N) {
  int i = blockIdx.x * 256 + threadIdx.x;
  if (i < N) {
    ns[i] = rsqrtf(fmaxf((float)dego[i], 1.f));
    nd[i] = rsqrtf(fmaxf((float)degi[i], 1.f));
  }
}

// ---- hierarchical exclusive scan: part -> scanp -> scat ----
// k_part: per-1024-element block sums, coalesced int4 loads
__global__ __launch_bounds__(256) void k_part(const int* __restrict__ deg,
                                              int* __restrict__ psum, int n) {
  int b = blockIdx.x, t = threadIdx.x;
  int i = b * 1024 + t * 4;
  int4 v = make_int4(0, 0, 0, 0);
  if (i + 3 < n) v = *(const int4*)(deg + i);
  else {
    if (i < n) v.x = deg[i];
    if (i + 1 < n) v.y = deg[i + 1];
    if (i + 2 < n) v.z = deg[i + 2];
    if (i + 3 < n) v.w = deg[i + 3];
  }
  int s = v.x + v.y + v.z + v.w;
#pragma unroll
  for (int off = 1; off < 64; off <<= 1) s += __shfl_xor(s, off);
  __shared__ int wsum[4];
  if ((t & 63) == 0) wsum[t >> 6] = s;
  __syncthreads();
  if (t == 0) psum[b] = wsum[0] + wsum[1] + wsum[2] + wsum[3];
}

// k_scanp: exclusive scan of psum[0..nb), nb <= 1024, single block
__global__ __launch_bounds__(1024) void k_scanp(int* __restrict__ psum, int nb) {
  __shared__ int buf[1024];
  int t = threadIdx.x;
  int v = (t < nb) ? psum[t] : 0;
  buf[t] = v;
  __syncthreads();
  for (int off = 1; off < 1024; off <<= 1) {
    int u = (t >= off) ? buf[t - off] : 0;
    __syncthreads();
    buf[t] += u;
    __syncthreads();
  }
  if (t < nb) psum[t] = buf[t] - v;
}

// k_scat: block-local scan + psum offset -> rp[0..n), plus rp[n]=total
__global__ __launch_bounds__(256) void k_scat(const int* __restrict__ deg,
                                              const int* __restrict__ psum,
                                              int* __restrict__ rp, int n, int nb) {
  int b = blockIdx.x, t = threadIdx.x;
  int i = b * 1024 + t * 4;
  int4 v = make_int4(0, 0, 0, 0);
  if (i + 3 < n) v = *(const int4*)(deg + i);
  else {
    if (i < n) v.x = deg[i];
    if (i + 1 < n) v.y = deg[i + 1];
    if (i + 2 < n) v.z = deg[i + 2];
    if (i + 3 < n) v.w = deg[i + 3];
  }
  int s = v.x + v.y + v.z + v.w;
  __shared__ int buf[256];
  buf[t] = s;
  __syncthreads();
  for (int off = 1; off < 256; off <<= 1) {
    int u = (t >= off) ? buf[t - off] : 0;
    __syncthreads();
    buf[t] += u;
    __syncthreads();
  }
  int ex = buf[t] - s + psum[b];
  int4 o;
  o.x = ex; o.y = ex + v.x; o.z = ex + v.x + v.y; o.w = ex + v.x + v.y + v.z;
  if (i + 3 < n) *(int4*)(rp + i) = o;
  else {
    if (i < n) rp[i] = o.x;
    if (i + 1 < n) rp[i + 1] = o.y;
    if (i + 2 < n) rp[i + 2] = o.z;
    if (i + 3 < n) rp[i + 3] = o.w;
  }
  if (b == nb - 1 && t == 255) rp[n] = ex + s;
}

__global__ void k_csr(const int* __restrict__ src, const int* __restrict__ dst,
                      const int* __restrict__ rp, int* __restrict__ cur,
                      int* __restrict__ csrc, int E) {
  int e = blockIdx.x * 256 + threadIdx.x;
  if (e < E) {
    int d = dst[e];
    int p = atomicAdd(&cur[d], 1);
    csrc[rp[d] + p] = src[e];
  }
}

__global__ void k_mcsr(const int* __restrict__ mid, const int* __restrict__ mrp,
                       int* __restrict__ cur, int* __restrict__ mlist, int N) {
  int n = blockIdx.x * 256 + threadIdx.x;
  if (n < N) {
    int m = mid[n];
    int p = atomicAdd(&cur[m], 1);
    mlist[mrp[m] + p] = n;
  }
}

// hw = (hn @ Wg) * norm_src, res = relu(hn @ Wr + br), hn = h*scale+shift (opt)
__global__ __launch_bounds__(256) void k_dualgemm(
    const float* __restrict__ h, const float* __restrict__ Wg,
    const float* __restrict__ Wr, const float* __restrict__ brl,
    const float* __restrict__ ns, const float* __restrict__ scale,
    const float* __restrict__ shift, float* __restrict__ hw,
    float* __restrict__ res, int N) {
  __shared__ float4 hs[32][32];  // 32 rows x 128 floats
  int t = threadIdx.x;
  int row0 = blockIdx.x * 32;
  for (int i = t; i < 1024; i += 256) {
    int r = i >> 5, c = i & 31;
    int gr = row0 + r;
    float4 v = make_float4(0.f, 0.f, 0.f, 0.f);
    if (gr < N) {
      v = ((const float4*)h)[(size_t)gr * 32 + c];
      if (scale) {
        float4 sc = ((const float4*)scale)[c];
        float4 sh = ((const float4*)shift)[c];
        v.x = v.x * sc.x + sh.x;
        v.y = v.y * sc.y + sh.y;
        v.z = v.z * sc.z + sh.z;
        v.w = v.w * sc.w + sh.w;
      }
    }
    hs[r][c] = v;
  }
  __syncthreads();
  const int rb = (t >> 5) * 4;
  const int j0 = (t & 31) * 4;
  float accg[4][4] = {};
  float accr[4][4] = {};
  for (int k4 = 0; k4 < 32; ++k4) {
    float a[4][4];
#pragma unroll
    for (int r = 0; r < 4; ++r) {
      float4 v = hs[rb + r][k4];
      a[r][0] = v.x; a[r][1] = v.y; a[r][2] = v.z; a[r][3] = v.w;
    }
#pragma unroll
    for (int kk = 0; kk < 4; ++kk) {
      int k = k4 * 4 + kk;
      float4 wg = *(const float4*)(Wg + k * D128 + j0);
      float4 wr = *(const float4*)(Wr + k * D128 + j0);
      float wga[4] = {wg.x, wg.y, wg.z, wg.w};
      float wra[4] = {wr.x, wr.y, wr.z, wr.w};
#pragma unroll
      for (int r = 0; r < 4; ++r) {
#pragma unroll
        for (int j = 0; j < 4; ++j) {
          accg[r][j] += a[r][kk] * wga[j];
          accr[r][j] += a[r][kk] * wra[j];
        }
      }
    }
  }
  float4 bb = *(const float4*)(brl + j0);
  float ba[4] = {bb.x, bb.y, bb.z, bb.w};
#pragma unroll
  for (int r = 0; r < 4; ++r) {
    int gr = row0 + rb + r;
    if (gr >= N) continue;
    float s = ns[gr];
    float4 og, orr;
    og.x = accg[r][0] * s; og.y = accg[r][1] * s;
    og.z = accg[r][2] * s; og.w = accg[r][3] * s;
    orr.x = fmaxf(accr[r][0] + ba[0], 0.f);
    orr.y = fmaxf(accr[r][1] + ba[1], 0.f);
    orr.z = fmaxf(accr[r][2] + ba[2], 0.f);
    orr.w = fmaxf(accr[r][3] + ba[3], 0.f);
    *(float4*)(hw + (size_t)gr * D128 + j0) = og;
    *(float4*)(res + (size_t)gr * D128 + j0) = orr;
  }
}

// one wave per node: y = relu(agg*nd + bg) + res, written over res (yres)
__global__ __launch_bounds__(256) void k_agg(
    const float* __restrict__ hw, const int* __restrict__ rp,
    const int* __restrict__ csrc, const float* __restrict__ nd,
    const float* __restrict__ bgl, float* __restrict__ yres, int N) {
  int n = blockIdx.x * 4 + (threadIdx.x >> 6);
  int lane = threadIdx.x & 63;
  if (n >= N) return;
  int beg = rp[n], end = rp[n + 1];
  float ax = 0.f, ay = 0.f;
  for (int e = beg; e < end; ++e) {
    int s = csrc[e];
    float2 v = ((const float2*)hw)[(size_t)s * 64 + lane];
    ax += v.x; ay += v.y;
  }
  float ndv = nd[n];
  float2 b = ((const float2*)bgl)[lane];
  float2 r = ((const float2*)yres)[(size_t)n * 64 + lane];
  float2 y;
  y.x = fmaxf(ax * ndv + b.x, 0.f) + r.x;
  y.y = fmaxf(ay * ndv + b.y, 0.f) + r.y;
  ((float2*)yres)[(size_t)n * 64 + lane] = y;
}

__global__ __launch_bounds__(256) void k_stats(const float* __restrict__ y,
                                               float* __restrict__ s1,
                                               float* __restrict__ s2, int N) {
  int t = threadIdx.x;
  int col = t & 127, half = t >> 7;
  float a = 0.f, q = 0.f;
  for (int r = blockIdx.x * 2 + half; r < N; r += gridDim.x * 2) {
    float v = y[(size_t)r * D128 + col];
    a += v; q += v * v;
  }
  __shared__ float ls[256], lq[256];
  ls[t] = a; lq[t] = q;
  __syncthreads();
  if (t < 128) {
    atomicAdd(&s1[col], ls[t] + ls[t + 128]);
    atomicAdd(&s2[col], lq[t] + lq[t + 128]);
  }
}

__global__ void k_bnfin(const float* __restrict__ s1, const float* __restrict__ s2,
                        const float* __restrict__ gam, const float* __restrict__ bet,
                        float* __restrict__ scale, float* __restrict__ shift, float invN) {
  int j = threadIdx.x;
  float mu = s1[j] * invN;
  float var = s2[j] * invN - mu * mu;
  float sc = gam[j] * rsqrtf(var + 1e-5f);
  scale[j] = sc;
  shift[j] = bet[j] - mu * sc;
}

// graph pooling on RAW yres, BN affine applied to means; writes d_out + xcat
__global__ __launch_bounds__(256) void k_poolg(const float* __restrict__ y,
                                               const int* __restrict__ gid,
                                               const float* __restrict__ scale,
                                               const float* __restrict__ shift,
                                               float* __restrict__ out,
                                               float* __restrict__ xcat, int N) {
  int g = blockIdx.x;
  int lo = 0, hi = N;
  while (lo < hi) { int m = (lo + hi) >> 1; if (gid[m] < g) lo = m + 1; else hi = m; }
  int beg = lo;
  hi = N;
  while (lo < hi) { int m = (lo + hi) >> 1; if (gid[m] <= g) lo = m + 1; else hi = m; }
  int end = lo;
  int t = threadIdx.x;
  int col = t & 127, half = t >> 7;
  float acc = 0.f;
  for (int r = beg + half; r < end; r += 2) acc += y[(size_t)r * D128 + col];
  __shared__ float ls[256];
  ls[t] = acc;
  __syncthreads();
  if (t < 128) {
    float v = ls[t] + ls[t + 128];
    v = v / fmaxf((float)(end - beg), 1.f);
    v = v * scale[t] + shift[t];
    out[(size_t)g * D128 + t] = v;
    xcat[(size_t)g * D128 + t] = v;
  }
}

// motif pooling via CSR gather: one block per motif m in [1..M]
__global__ __launch_bounds__(256) void k_poolmg(const float* __restrict__ y,
                                                const int* __restrict__ mrp,
                                                const int* __restrict__ mlist,
                                                const float* __restrict__ scale,
                                                const float* __restrict__ shift,
                                                float* __restrict__ xsub, int M) {
  int m = blockIdx.x + 1;
  int beg = mrp[m], end = mrp[m + 1];
  int t = threadIdx.x;
  int col = t & 127, half = t >> 7;
  float acc = 0.f;
  for (int r = beg + half; r < end; r += 2) {
    int n = mlist[r];
    acc += y[(size_t)n * D128 + col];
  }
  __shared__ float ls[256];
  ls[t] = acc;
  __syncthreads();
  if (t < 128) {
    float v = ls[t] + ls[t + 128];
    v = v / fmaxf((float)(end - beg), 1.f);
    v = v * scale[t] + shift[t];
    xsub[(size_t)(m - 1) * D128 + t] = v;
  }
}

// tiled GEMM: out = act(X[M,K] @ W[K,N] + b), BM=64 BN=64 BK=32, 256 thr, 4x4/thr
__global__ __launch_bounds__(256) void k_gemm64(
    const float* __restrict__ X, const float* __restrict__ W,
    const float* __restrict__ b, float* __restrict__ out,
    int Mrows, int K, int Ncols, int relu) {
  __shared__ float xs[64][33];
  __shared__ float ws[32][68];
  int t = threadIdx.x;
  int row0 = blockIdx.x * 64, col0 = blockIdx.y * 64;
  int tx = t & 15, ty = t >> 4;
  int j0 = tx * 4, r0 = ty * 4;
  float acc[4][4] = {};
  for (int k0 = 0; k0 < K; k0 += 32) {
    for (int i = t; i < 512; i += 256) {
      int r = i >> 3, c4 = i & 7;
      int gr = row0 + r;
      float4 v = make_float4(0.f, 0.f, 0.f, 0.f);
      if (gr < Mrows) v = *(const float4*)(X + (size_t)gr * K + k0 + c4 * 4);
      xs[r][c4 * 4 + 0] = v.x; xs[r][c4 * 4 + 1] = v.y;
      xs[r][c4 * 4 + 2] = v.z; xs[r][c4 * 4 + 3] = v.w;
    }
    for (int i = t; i < 512; i += 256) {
      int r = i >> 4, c4 = i & 15;
      float4 v = *(const float4*)(W + (size_t)(k0 + r) * Ncols + col0 + c4 * 4);
      *(float4*)(&ws[r][c4 * 4]) = v;
    }
    __syncthreads();
#pragma unroll
    for (int kk = 0; kk < 32; ++kk) {
      float a_[4];
#pragma unroll
      for (int r = 0; r < 4; ++r) a_[r] = xs[r0 + r][kk];
      float4 wv = *(const float4*)(&ws[kk][j0]);
      float b_[4] = {wv.x, wv.y, wv.z, wv.w};
#pragma unroll
      for (int r = 0; r < 4; ++r)
#pragma unroll
        for (int j = 0; j < 4; ++j) acc[r][j] += a_[r] * b_[j];
    }
    __syncthreads();
  }
  float4 bb = *(const float4*)(b + col0 + j0);
  float ba[4] = {bb.x, bb.y, bb.z, bb.w};
#pragma unroll
  for (int r = 0; r < 4; ++r) {
    int gr = row0 + r0 + r;
    if (gr >= Mrows) continue;
    float4 o;
    o.x = acc[r][0] + ba[0]; o.y = acc[r][1] + ba[1];
    o.z = acc[r][2] + ba[2]; o.w = acc[r][3] + ba[3];
    if (relu) {
      o.x = fmaxf(o.x, 0.f); o.y = fmaxf(o.y, 0.f);
      o.z = fmaxf(o.z, 0.f); o.w = fmaxf(o.w, 0.f);
    }
    *(float4*)(out + (size_t)gr * Ncols + col0 + j0) = o;
  }
}

extern "C" void kernel_launch(void* const* d_in, const int* in_sizes, int n_in,
                              void* d_out, int out_size, void* d_ws, size_t ws_size,
                              hipStream_t stream) {
  (void)n_in; (void)out_size; (void)ws_size;
  const float* nf   = (const float*)d_in[0];
  const int*   src  = (const int*)d_in[1];
  const int*   dst  = (const int*)d_in[2];
  const int*   gid  = (const int*)d_in[3];
  const int*   mid  = (const int*)d_in[4];
  const float* Wg   = (const float*)d_in[5];
  const float* bg   = (const float*)d_in[6];
  const float* Wr   = (const float*)d_in[7];
  const float* br   = (const float*)d_in[8];
  const float* gam  = (const float*)d_in[9];
  const float* bet  = (const float*)d_in[10];
  const float* Wf   = (const float*)d_in[11];
  const float* bf   = (const float*)d_in[12];
  const float* W1   = (const float*)d_in[13];
  const float* b1   = (const float*)d_in[14];
  const float* W2   = (const float*)d_in[15];
  const float* b2   = (const float*)d_in[16];

  const int N = in_sizes[0] / D128;
  const int E = in_sizes[1];
  const int G = 512;
  const int M = 2048;
  const int R = G + M;  // 2560 batched head rows

  char* ws = (char*)d_ws;
  size_t off = 0;
  auto alloc = [&](size_t bytes) -> void* {
    void* p = ws + off;
    off = (off + bytes + 255) & ~(size_t)255;
    return p;
  };
  float* hw   = (float*)alloc((size_t)N * D128 * 4);
  float* yres = (float*)alloc((size_t)N * D128 * 4);
  // one contiguous zero block: dego | degi | cur | cntm | mcur
  int*   zblk = (int*)alloc((size_t)(3 * N + 2 * (M + 1)) * 4);
  int*   dego = zblk;
  int*   degi = zblk + N;
  int*   cur  = zblk + 2 * N;
  int*   cntm = zblk + 3 * N;
  int*   mcur = zblk + 3 * N + (M + 1);
  float* ns   = (float*)alloc((size_t)N * 4);
  float* nd   = (float*)alloc((size_t)N * 4);
  int*   rp   = (int*)alloc((size_t)(N + 1) * 4);
  int*   mrp  = (int*)alloc((size_t)(M + 2) * 4);
  int*   csrc = (int*)alloc((size_t)E * 4);
  int*   mlist= (int*)alloc((size_t)N * 4);
  int*   psum = (int*)alloc(1024 * 4);
  float* s12  = (float*)alloc(256 * 4);
  float* scsh = (float*)alloc(256 * 4);
  float* xcat = (float*)alloc((size_t)R * D128 * 4);
  float* fbuf = (float*)alloc((size_t)R * 256 * 4);
  float* zbuf = (float*)alloc((size_t)R * 256 * 4);

  float* outg  = (float*)d_out;             // graph_feats [512,128]
  float* outgl = outg + (size_t)G * D128;   // out_global [512,128] then out_sub [2048,128]

  hipMemsetAsync(zblk, 0, (size_t)(3 * N + 2 * (M + 1)) * 4, stream);

  k_deg<<<(E + 255) / 256, 256, 0, stream>>>(src, dst, dego, degi, E);
  k_hist_m<<<(N + 255) / 256, 256, 0, stream>>>(mid, cntm, N);
  k_norm<<<(N + 255) / 256, 256, 0, stream>>>(dego, degi, ns, nd, N);

  // hierarchical scan: degi -> rp  (nb1 blocks of 1024)
  int nb1 = (N + 1023) / 1024;
  k_part<<<nb1, 256, 0, stream>>>(degi, psum, N);
  k_scanp<<<1, 1024, 0, stream>>>(psum, nb1);
  k_scat<<<nb1, 256, 0, stream>>>(degi, psum, rp, N, nb1);
  k_csr<<<(E + 255) / 256, 256, 0, stream>>>(src, dst, rp, cur, csrc, E);

  // hierarchical scan: cntm -> mrp  (M+1 entries)
  int nb2 = (M + 1 + 1023) / 1024;
  k_part<<<nb2, 256, 0, stream>>>(cntm, psum, M + 1);
  k_scanp<<<1, 1024, 0, stream>>>(psum, nb2);
  k_scat<<<nb2, 256, 0, stream>>>(cntm, psum, mrp, M + 1, nb2);
  k_mcsr<<<(N + 255) / 256, 256, 0, stream>>>(mid, mrp, mcur, mlist, N);

  const float* hin = nf;
  for (int l = 0; l < 3; ++l) {
    const float* sc = (l == 0) ? nullptr : scsh;
    const float* sh = (l == 0) ? nullptr : (scsh + 128);
    k_dualgemm<<<(N + 31) / 32, 256, 0, stream>>>(hin, Wg + l * 16384, Wr + l * 16384,
                                                  br + l * D128, ns, sc, sh, hw, yres, N);
    k_agg<<<(N + 3) / 4, 256, 0, stream>>>(hw, rp, csrc, nd, bg + l * D128, yres, N);
    hipMemsetAsync(s12, 0, 256 * 4, stream);
    k_stats<<<256, 256, 0, stream>>>(yres, s12, s12 + 128, N);
    k_bnfin<<<1, 128, 0, stream>>>(s12, s12 + 128, gam + l * D128, bet + l * D128,
                                   scsh, scsh + 128, 1.f / (float)N);
    hin = yres;
  }

  // pooled readouts on RAW yres, BN affine applied to the means
  k_poolg<<<G, 256, 0, stream>>>(yres, gid, scsh, scsh + 128, outg, xcat, N);
  k_poolmg<<<M, 256, 0, stream>>>(yres, mrp, mlist, scsh, scsh + 128,
                                  xcat + (size_t)G * D128, M);

  // batched head on xcat [2560,128]: 3 GEMMs; final writes d_out directly
  dim3 g1((R + 63) / 64, 256 / 64);
  k_gemm64<<<g1, 256, 0, stream>>>(xcat, Wf, bf, fbuf, R, 128, 256, 0);
  dim3 g2((R + 63) / 64, 256 / 64);
  k_gemm64<<<g2, 256, 0, stream>>>(fbuf, W1, b1, zbuf, R, 256, 256, 1);
  dim3 g3((R + 63) / 64, 128 / 64);
  k_gemm64<<<g3, 256, 0, stream>>>(zbuf, W2, b2, outgl, R, 256, 128, 0);
}

// Round 6
// 678.948 us; speedup vs baseline: 1.7069x; 1.1782x over previous
//
#include <hip/hip_runtime.h>

// ---------------------------------------------------------------------------
// GCN forward: 3x (split-bf16 MFMA dual GEMM -> edge gather-agg -> BN-fused)
// -> CSR pooled readouts -> batched MLP head.
// Round 4/5: dual GEMM on matrix cores via f32 = bf16_hi + bf16_lo split
// (3 MFMAs per product term); weights pre-packed in fragment order.
// (Round-5 resubmit: round-4 bench was an infra failure, kernel never ran.)
// ---------------------------------------------------------------------------

#define D128 128

typedef short bf16x8 __attribute__((ext_vector_type(8)));
typedef unsigned short u16x8 __attribute__((ext_vector_type(8)));
typedef float f32x4 __attribute__((ext_vector_type(4)));

static __device__ __forceinline__ unsigned short f2bf(float x) {
  unsigned u = __float_as_uint(x);
  unsigned r = (u + 0x7FFF + ((u >> 16) & 1)) >> 16;  // RNE
  return (unsigned short)r;
}
static __device__ __forceinline__ float bf2f(unsigned short b) {
  return __uint_as_float(((unsigned)b) << 16);
}

__global__ void k_deg(const int* __restrict__ src, const int* __restrict__ dst,
                      int* __restrict__ dego, int* __restrict__ degi, int E) {
  int e = blockIdx.x * 256 + threadIdx.x;
  if (e < E) {
    atomicAdd(&dego[src[e]], 1);
    atomicAdd(&degi[dst[e]], 1);
  }
}

__global__ void k_hist_m(const int* __restrict__ mid, int* __restrict__ cntm, int N) {
  int i = blockIdx.x * 256 + threadIdx.x;
  if (i < N) atomicAdd(&cntm[mid[i]], 1);
}

__global__ void k_norm(const int* __restrict__ dego, const int* __restrict__ degi,
                       float* __restrict__ ns, float* __restrict__ nd, int N) {
  int i = blockIdx.x * 256 + threadIdx.x;
  if (i < N) {
    ns[i] = rsqrtf(fmaxf((float)dego[i], 1.f));
    nd[i] = rsqrtf(fmaxf((float)degi[i], 1.f));
  }
}

// ---- hierarchical exclusive scan: part -> scanp -> scat ----
__global__ __launch_bounds__(256) void k_part(const int* __restrict__ deg,
                                              int* __restrict__ psum, int n) {
  int b = blockIdx.x, t = threadIdx.x;
  int i = b * 1024 + t * 4;
  int4 v = make_int4(0, 0, 0, 0);
  if (i + 3 < n) v = *(const int4*)(deg + i);
  else {
    if (i < n) v.x = deg[i];
    if (i + 1 < n) v.y = deg[i + 1];
    if (i + 2 < n) v.z = deg[i + 2];
    if (i + 3 < n) v.w = deg[i + 3];
  }
  int s = v.x + v.y + v.z + v.w;
#pragma unroll
  for (int off = 1; off < 64; off <<= 1) s += __shfl_xor(s, off);
  __shared__ int wsum[4];
  if ((t & 63) == 0) wsum[t >> 6] = s;
  __syncthreads();
  if (t == 0) psum[b] = wsum[0] + wsum[1] + wsum[2] + wsum[3];
}

__global__ __launch_bounds__(1024) void k_scanp(int* __restrict__ psum, int nb) {
  __shared__ int buf[1024];
  int t = threadIdx.x;
  int v = (t < nb) ? psum[t] : 0;
  buf[t] = v;
  __syncthreads();
  for (int off = 1; off < 1024; off <<= 1) {
    int u = (t >= off) ? buf[t - off] : 0;
    __syncthreads();
    buf[t] += u;
    __syncthreads();
  }
  if (t < nb) psum[t] = buf[t] - v;
}

__global__ __launch_bounds__(256) void k_scat(const int* __restrict__ deg,
                                              const int* __restrict__ psum,
                                              int* __restrict__ rp, int n, int nb) {
  int b = blockIdx.x, t = threadIdx.x;
  int i = b * 1024 + t * 4;
  int4 v = make_int4(0, 0, 0, 0);
  if (i + 3 < n) v = *(const int4*)(deg + i);
  else {
    if (i < n) v.x = deg[i];
    if (i + 1 < n) v.y = deg[i + 1];
    if (i + 2 < n) v.z = deg[i + 2];
    if (i + 3 < n) v.w = deg[i + 3];
  }
  int s = v.x + v.y + v.z + v.w;
  __shared__ int buf[256];
  buf[t] = s;
  __syncthreads();
  for (int off = 1; off < 256; off <<= 1) {
    int u = (t >= off) ? buf[t - off] : 0;
    __syncthreads();
    buf[t] += u;
    __syncthreads();
  }
  int ex = buf[t] - s + psum[b];
  int4 o;
  o.x = ex; o.y = ex + v.x; o.z = ex + v.x + v.y; o.w = ex + v.x + v.y + v.z;
  if (i + 3 < n) *(int4*)(rp + i) = o;
  else {
    if (i < n) rp[i] = o.x;
    if (i + 1 < n) rp[i + 1] = o.y;
    if (i + 2 < n) rp[i + 2] = o.z;
    if (i + 3 < n) rp[i + 3] = o.w;
  }
  if (b == nb - 1 && t == 255) rp[n] = ex + s;
}

__global__ void k_csr(const int* __restrict__ src, const int* __restrict__ dst,
                      const int* __restrict__ rp, int* __restrict__ cur,
                      int* __restrict__ csrc, int E) {
  int e = blockIdx.x * 256 + threadIdx.x;
  if (e < E) {
    int d = dst[e];
    int p = atomicAdd(&cur[d], 1);
    csrc[rp[d] + p] = src[e];
  }
}

__global__ void k_mcsr(const int* __restrict__ mid, const int* __restrict__ mrp,
                       int* __restrict__ cur, int* __restrict__ mlist, int N) {
  int n = blockIdx.x * 256 + threadIdx.x;
  if (n < N) {
    int m = mid[n];
    int p = atomicAdd(&cur[m], 1);
    mlist[mrp[m] + p] = n;
  }
}

// pack W (3 layers x {Wg,Wr}) into MFMA B-fragment order, bf16 hi/lo.
// Per (l,mat): hi[16384] then lo[16384] ushorts. Frag fs = cb*4+s (cb 0..7, s 0..3):
// element j of lane: W[k = s*32 + (lane>>4)*8 + j][n = cb*16 + (lane&15)]
__global__ __launch_bounds__(256) void k_wprep(const float* __restrict__ Wg,
                                               const float* __restrict__ Wr,
                                               unsigned short* __restrict__ wp) {
  int idx = blockIdx.x * 256 + threadIdx.x;
  if (idx >= 3 * 2 * 2048) return;
  int lane = idx & 63;
  int fs = (idx >> 6) & 31;
  int m = (idx >> 11) & 1;
  int l = idx >> 12;
  int cb = fs >> 2, s = fs & 3;
  const float* W = (m == 0 ? Wg : Wr) + (size_t)l * 16384;
  int n = cb * 16 + (lane & 15);
  int k0 = s * 32 + (lane >> 4) * 8;
  unsigned short* hi = wp + ((size_t)(l * 2 + m)) * 32768 + ((size_t)fs * 64 + lane) * 8;
  unsigned short* lo = hi + 16384;
#pragma unroll
  for (int j = 0; j < 8; ++j) {
    float x = W[(size_t)(k0 + j) * D128 + n];
    unsigned short h = f2bf(x);
    hi[j] = h;
    lo[j] = f2bf(x - bf2f(h));
  }
}

// split-bf16 MFMA dual GEMM: 64 rows x 256 cols (Wg|Wr) per block, 4 waves.
// hw = (hn @ Wg) * ns, res = relu(hn @ Wr + br), hn = h*scale+shift (opt)
__global__ __launch_bounds__(256) void k_dualmfma(
    const float* __restrict__ h, const unsigned short* __restrict__ wpl,
    const float* __restrict__ brl, const float* __restrict__ ns,
    const float* __restrict__ scale, const float* __restrict__ shift,
    float* __restrict__ hw, float* __restrict__ res, int N) {
  __shared__ __align__(16) unsigned char smem[32768];  // hi[64][256B] | lo
  int t = threadIdx.x;
  int row0 = blockIdx.x * 64;

  // stage 64x128 f32 -> bf16 hi/lo in LDS, XOR-swizzled (byte ^= (row&7)<<4)
#pragma unroll
  for (int q = 0; q < 4; ++q) {
    int chunk = q * 256 + t;      // 1024 chunks of 8 elems
    int r = chunk >> 4;
    int c8 = chunk & 15;
    int gr = row0 + r;
    float xs[8];
    if (gr < N) {
      const float4* hp = (const float4*)(h + (size_t)gr * D128 + c8 * 8);
      float4 v0 = hp[0], v1 = hp[1];
      xs[0] = v0.x; xs[1] = v0.y; xs[2] = v0.z; xs[3] = v0.w;
      xs[4] = v1.x; xs[5] = v1.y; xs[6] = v1.z; xs[7] = v1.w;
      if (scale) {
        float4 sc0 = ((const float4*)scale)[c8 * 2];
        float4 sc1 = ((const float4*)scale)[c8 * 2 + 1];
        float4 sh0 = ((const float4*)shift)[c8 * 2];
        float4 sh1 = ((const float4*)shift)[c8 * 2 + 1];
        xs[0] = xs[0] * sc0.x + sh0.x; xs[1] = xs[1] * sc0.y + sh0.y;
        xs[2] = xs[2] * sc0.z + sh0.z; xs[3] = xs[3] * sc0.w + sh0.w;
        xs[4] = xs[4] * sc1.x + sh1.x; xs[5] = xs[5] * sc1.y + sh1.y;
        xs[6] = xs[6] * sc1.z + sh1.z; xs[7] = xs[7] * sc1.w + sh1.w;
      }
    } else {
#pragma unroll
      for (int j = 0; j < 8; ++j) xs[j] = 0.f;
    }
    u16x8 hi8, lo8;
#pragma unroll
    for (int j = 0; j < 8; ++j) {
      unsigned short hb = f2bf(xs[j]);
      hi8[j] = hb;
      lo8[j] = f2bf(xs[j] - bf2f(hb));
    }
    int sw = (c8 * 16) ^ ((r & 7) << 4);
    *(u16x8*)(&smem[r * 256 + sw]) = hi8;
    *(u16x8*)(&smem[16384 + r * 256 + sw]) = lo8;
  }
  __syncthreads();

  int w = t >> 6, l6 = t & 63;
  int mat = w >> 1, half = w & 1;
  const unsigned short* wpm = wpl + (size_t)mat * 32768;

  f32x4 acc[4][4];
#pragma unroll
  for (int rb = 0; rb < 4; ++rb)
#pragma unroll
    for (int cb = 0; cb < 4; ++cb) acc[rb][cb] = (f32x4){0.f, 0.f, 0.f, 0.f};

#pragma unroll
  for (int s = 0; s < 4; ++s) {
    bf16x8 ah[4], al[4];
    int kb = s * 64 + (l6 >> 4) * 16;
#pragma unroll
    for (int rb = 0; rb < 4; ++rb) {
      int row = rb * 16 + (l6 & 15);
      int off = row * 256 + (kb ^ ((row & 7) << 4));
      ah[rb] = *(const bf16x8*)(&smem[off]);
      al[rb] = *(const bf16x8*)(&smem[16384 + off]);
    }
    bf16x8 bh[4], bl[4];
#pragma unroll
    for (int cb = 0; cb < 4; ++cb) {
      const unsigned short* p = wpm + (((size_t)(half * 4 + cb) * 4 + s) * 64 + l6) * 8;
      bh[cb] = *(const bf16x8*)p;
      bl[cb] = *(const bf16x8*)(p + 16384);
    }
#pragma unroll
    for (int rb = 0; rb < 4; ++rb)
#pragma unroll
      for (int cb = 0; cb < 4; ++cb) {
        acc[rb][cb] = __builtin_amdgcn_mfma_f32_16x16x32_bf16(ah[rb], bh[cb], acc[rb][cb], 0, 0, 0);
        acc[rb][cb] = __builtin_amdgcn_mfma_f32_16x16x32_bf16(al[rb], bh[cb], acc[rb][cb], 0, 0, 0);
        acc[rb][cb] = __builtin_amdgcn_mfma_f32_16x16x32_bf16(ah[rb], bl[cb], acc[rb][cb], 0, 0, 0);
      }
  }

  // epilogue: D row = (l6>>4)*4 + reg, col = l6&15  (m89-verified)
  int rsub = (l6 >> 4) * 4;
  int colb = half * 64 + (l6 & 15);
  if (mat == 0) {
#pragma unroll
    for (int rb = 0; rb < 4; ++rb)
#pragma unroll
      for (int reg = 0; reg < 4; ++reg) {
        int gr = row0 + rb * 16 + rsub + reg;
        if (gr >= N) continue;
        float sv = ns[gr];
        float* op = hw + (size_t)gr * D128 + colb;
#pragma unroll
        for (int cb = 0; cb < 4; ++cb) op[cb * 16] = acc[rb][cb][reg] * sv;
      }
  } else {
    float bv[4];
#pragma unroll
    for (int cb = 0; cb < 4; ++cb) bv[cb] = brl[colb + cb * 16];
#pragma unroll
    for (int rb = 0; rb < 4; ++rb)
#pragma unroll
      for (int reg = 0; reg < 4; ++reg) {
        int gr = row0 + rb * 16 + rsub + reg;
        if (gr >= N) continue;
        float* op = res + (size_t)gr * D128 + colb;
#pragma unroll
        for (int cb = 0; cb < 4; ++cb) op[cb * 16] = fmaxf(acc[rb][cb][reg] + bv[cb], 0.f);
      }
  }
}

// one wave per node: y = relu(agg*nd + bg) + res, written over res (yres)
__global__ __launch_bounds__(256) void k_agg(
    const float* __restrict__ hw, const int* __restrict__ rp,
    const int* __restrict__ csrc, const float* __restrict__ nd,
    const float* __restrict__ bgl, float* __restrict__ yres, int N) {
  int n = blockIdx.x * 4 + (threadIdx.x >> 6);
  int lane = threadIdx.x & 63;
  if (n >= N) return;
  int beg = rp[n], end = rp[n + 1];
  float ax = 0.f, ay = 0.f;
  for (int e = beg; e < end; ++e) {
    int s = csrc[e];
    float2 v = ((const float2*)hw)[(size_t)s * 64 + lane];
    ax += v.x; ay += v.y;
  }
  float ndv = nd[n];
  float2 b = ((const float2*)bgl)[lane];
  float2 r = ((const float2*)yres)[(size_t)n * 64 + lane];
  float2 y;
  y.x = fmaxf(ax * ndv + b.x, 0.f) + r.x;
  y.y = fmaxf(ay * ndv + b.y, 0.f) + r.y;
  ((float2*)yres)[(size_t)n * 64 + lane] = y;
}

__global__ __launch_bounds__(256) void k_stats(const float* __restrict__ y,
                                               float* __restrict__ s1,
                                               float* __restrict__ s2, int N) {
  int t = threadIdx.x;
  int col = t & 127, half = t >> 7;
  float a = 0.f, q = 0.f;
  for (int r = blockIdx.x * 2 + half; r < N; r += gridDim.x * 2) {
    float v = y[(size_t)r * D128 + col];
    a += v; q += v * v;
  }
  __shared__ float ls[256], lq[256];
  ls[t] = a; lq[t] = q;
  __syncthreads();
  if (t < 128) {
    atomicAdd(&s1[col], ls[t] + ls[t + 128]);
    atomicAdd(&s2[col], lq[t] + lq[t + 128]);
  }
}

__global__ void k_bnfin(const float* __restrict__ s1, const float* __restrict__ s2,
                        const float* __restrict__ gam, const float* __restrict__ bet,
                        float* __restrict__ scale, float* __restrict__ shift, float invN) {
  int j = threadIdx.x;
  float mu = s1[j] * invN;
  float var = s2[j] * invN - mu * mu;
  float sc = gam[j] * rsqrtf(var + 1e-5f);
  scale[j] = sc;
  shift[j] = bet[j] - mu * sc;
}

// graph pooling on RAW yres, BN affine applied to means; writes d_out + xcat
__global__ __launch_bounds__(256) void k_poolg(const float* __restrict__ y,
                                               const int* __restrict__ gid,
                                               const float* __restrict__ scale,
                                               const float* __restrict__ shift,
                                               float* __restrict__ out,
                                               float* __restrict__ xcat, int N) {
  int g = blockIdx.x;
  int lo = 0, hi = N;
  while (lo < hi) { int m = (lo + hi) >> 1; if (gid[m] < g) lo = m + 1; else hi = m; }
  int beg = lo;
  hi = N;
  while (lo < hi) { int m = (lo + hi) >> 1; if (gid[m] <= g) lo = m + 1; else hi = m; }
  int end = lo;
  int t = threadIdx.x;
  int col = t & 127, half = t >> 7;
  float acc = 0.f;
  for (int r = beg + half; r < end; r += 2) acc += y[(size_t)r * D128 + col];
  __shared__ float ls[256];
  ls[t] = acc;
  __syncthreads();
  if (t < 128) {
    float v = ls[t] + ls[t + 128];
    v = v / fmaxf((float)(end - beg), 1.f);
    v = v * scale[t] + shift[t];
    out[(size_t)g * D128 + t] = v;
    xcat[(size_t)g * D128 + t] = v;
  }
}

// motif pooling via CSR gather: one block per motif m in [1..M]
__global__ __launch_bounds__(256) void k_poolmg(const float* __restrict__ y,
                                                const int* __restrict__ mrp,
                                                const int* __restrict__ mlist,
                                                const float* __restrict__ scale,
                                                const float* __restrict__ shift,
                                                float* __restrict__ xsub, int M) {
  int m = blockIdx.x + 1;
  int beg = mrp[m], end = mrp[m + 1];
  int t = threadIdx.x;
  int col = t & 127, half = t >> 7;
  float acc = 0.f;
  for (int r = beg + half; r < end; r += 2) {
    int n = mlist[r];
    acc += y[(size_t)n * D128 + col];
  }
  __shared__ float ls[256];
  ls[t] = acc;
  __syncthreads();
  if (t < 128) {
    float v = ls[t] + ls[t + 128];
    v = v / fmaxf((float)(end - beg), 1.f);
    v = v * scale[t] + shift[t];
    xsub[(size_t)(m - 1) * D128 + t] = v;
  }
}

// tiled GEMM: out = act(X[M,K] @ W[K,N] + b), BM=64 BN=64 BK=32, 256 thr, 4x4/thr
__global__ __launch_bounds__(256) void k_gemm64(
    const float* __restrict__ X, const float* __restrict__ W,
    const float* __restrict__ b, float* __restrict__ out,
    int Mrows, int K, int Ncols, int relu) {
  __shared__ float xs[64][33];
  __shared__ float ws[32][68];
  int t = threadIdx.x;
  int row0 = blockIdx.x * 64, col0 = blockIdx.y * 64;
  int tx = t & 15, ty = t >> 4;
  int j0 = tx * 4, r0 = ty * 4;
  float acc[4][4] = {};
  for (int k0 = 0; k0 < K; k0 += 32) {
    for (int i = t; i < 512; i += 256) {
      int r = i >> 3, c4 = i & 7;
      int gr = row0 + r;
      float4 v = make_float4(0.f, 0.f, 0.f, 0.f);
      if (gr < Mrows) v = *(const float4*)(X + (size_t)gr * K + k0 + c4 * 4);
      xs[r][c4 * 4 + 0] = v.x; xs[r][c4 * 4 + 1] = v.y;
      xs[r][c4 * 4 + 2] = v.z; xs[r][c4 * 4 + 3] = v.w;
    }
    for (int i = t; i < 512; i += 256) {
      int r = i >> 4, c4 = i & 15;
      float4 v = *(const float4*)(W + (size_t)(k0 + r) * Ncols + col0 + c4 * 4);
      *(float4*)(&ws[r][c4 * 4]) = v;
    }
    __syncthreads();
#pragma unroll
    for (int kk = 0; kk < 32; ++kk) {
      float a_[4];
#pragma unroll
      for (int r = 0; r < 4; ++r) a_[r] = xs[r0 + r][kk];
      float4 wv = *(const float4*)(&ws[kk][j0]);
      float b_[4] = {wv.x, wv.y, wv.z, wv.w};
#pragma unroll
      for (int r = 0; r < 4; ++r)
#pragma unroll
        for (int j = 0; j < 4; ++j) acc[r][j] += a_[r] * b_[j];
    }
    __syncthreads();
  }
  float4 bb = *(const float4*)(b + col0 + j0);
  float ba[4] = {bb.x, bb.y, bb.z, bb.w};
#pragma unroll
  for (int r = 0; r < 4; ++r) {
    int gr = row0 + r0 + r;
    if (gr >= Mrows) continue;
    float4 o;
    o.x = acc[r][0] + ba[0]; o.y = acc[r][1] + ba[1];
    o.z = acc[r][2] + ba[2]; o.w = acc[r][3] + ba[3];
    if (relu) {
      o.x = fmaxf(o.x, 0.f); o.y = fmaxf(o.y, 0.f);
      o.z = fmaxf(o.z, 0.f); o.w = fmaxf(o.w, 0.f);
    }
    *(float4*)(out + (size_t)gr * Ncols + col0 + j0) = o;
  }
}

extern "C" void kernel_launch(void* const* d_in, const int* in_sizes, int n_in,
                              void* d_out, int out_size, void* d_ws, size_t ws_size,
                              hipStream_t stream) {
  (void)n_in; (void)out_size; (void)ws_size;
  const float* nf   = (const float*)d_in[0];
  const int*   src  = (const int*)d_in[1];
  const int*   dst  = (const int*)d_in[2];
  const int*   gid  = (const int*)d_in[3];
  const int*   mid  = (const int*)d_in[4];
  const float* Wg   = (const float*)d_in[5];
  const float* bg   = (const float*)d_in[6];
  const float* Wr   = (const float*)d_in[7];
  const float* br   = (const float*)d_in[8];
  const float* gam  = (const float*)d_in[9];
  const float* bet  = (const float*)d_in[10];
  const float* Wf   = (const float*)d_in[11];
  const float* bf   = (const float*)d_in[12];
  const float* W1   = (const float*)d_in[13];
  const float* b1   = (const float*)d_in[14];
  const float* W2   = (const float*)d_in[15];
  const float* b2   = (const float*)d_in[16];

  const int N = in_sizes[0] / D128;
  const int E = in_sizes[1];
  const int G = 512;
  const int M = 2048;
  const int R = G + M;  // 2560 batched head rows

  char* ws = (char*)d_ws;
  size_t off = 0;
  auto alloc = [&](size_t bytes) -> void* {
    void* p = ws + off;
    off = (off + bytes + 255) & ~(size_t)255;
    return p;
  };
  float* hw   = (float*)alloc((size_t)N * D128 * 4);
  float* yres = (float*)alloc((size_t)N * D128 * 4);
  // one contiguous zero block: dego | degi | cur | cntm | mcur
  int*   zblk = (int*)alloc((size_t)(3 * N + 2 * (M + 1)) * 4);
  int*   dego = zblk;
  int*   degi = zblk + N;
  int*   cur  = zblk + 2 * N;
  int*   cntm = zblk + 3 * N;
  int*   mcur = zblk + 3 * N + (M + 1);
  float* ns   = (float*)alloc((size_t)N * 4);
  float* nd   = (float*)alloc((size_t)N * 4);
  int*   rp   = (int*)alloc((size_t)(N + 1) * 4);
  int*   mrp  = (int*)alloc((size_t)(M + 2) * 4);
  int*   csrc = (int*)alloc((size_t)E * 4);
  int*   mlist= (int*)alloc((size_t)N * 4);
  int*   psum = (int*)alloc(1024 * 4);
  float* s12  = (float*)alloc(256 * 4);
  float* scsh = (float*)alloc(256 * 4);
  unsigned short* wp = (unsigned short*)alloc((size_t)3 * 2 * 2 * 16384 * 2);
  float* xcat = (float*)alloc((size_t)R * D128 * 4);
  float* fbuf = (float*)alloc((size_t)R * 256 * 4);
  float* zbuf = (float*)alloc((size_t)R * 256 * 4);

  float* outg  = (float*)d_out;             // graph_feats [512,128]
  float* outgl = outg + (size_t)G * D128;   // out_global [512,128] then out_sub [2048,128]

  hipMemsetAsync(zblk, 0, (size_t)(3 * N + 2 * (M + 1)) * 4, stream);

  k_deg<<<(E + 255) / 256, 256, 0, stream>>>(src, dst, dego, degi, E);
  k_hist_m<<<(N + 255) / 256, 256, 0, stream>>>(mid, cntm, N);
  k_norm<<<(N + 255) / 256, 256, 0, stream>>>(dego, degi, ns, nd, N);
  k_wprep<<<(3 * 2 * 2048 + 255) / 256, 256, 0, stream>>>(Wg, Wr, wp);

  // hierarchical scan: degi -> rp
  int nb1 = (N + 1023) / 1024;
  k_part<<<nb1, 256, 0, stream>>>(degi, psum, N);
  k_scanp<<<1, 1024, 0, stream>>>(psum, nb1);
  k_scat<<<nb1, 256, 0, stream>>>(degi, psum, rp, N, nb1);
  k_csr<<<(E + 255) / 256, 256, 0, stream>>>(src, dst, rp, cur, csrc, E);

  // hierarchical scan: cntm -> mrp
  int nb2 = (M + 1 + 1023) / 1024;
  k_part<<<nb2, 256, 0, stream>>>(cntm, psum, M + 1);
  k_scanp<<<1, 1024, 0, stream>>>(psum, nb2);
  k_scat<<<nb2, 256, 0, stream>>>(cntm, psum, mrp, M + 1, nb2);
  k_mcsr<<<(N + 255) / 256, 256, 0, stream>>>(mid, mrp, mcur, mlist, N);

  const float* hin = nf;
  for (int l = 0; l < 3; ++l) {
    const float* sc = (l == 0) ? nullptr : scsh;
    const float* sh = (l == 0) ? nullptr : (scsh + 128);
    k_dualmfma<<<(N + 63) / 64, 256, 0, stream>>>(hin, wp + (size_t)l * 65536,
                                                  br + l * D128, ns, sc, sh, hw, yres, N);
    k_agg<<<(N + 3) / 4, 256, 0, stream>>>(hw, rp, csrc, nd, bg + l * D128, yres, N);
    hipMemsetAsync(s12, 0, 256 * 4, stream);
    k_stats<<<256, 256, 0, stream>>>(yres, s12, s12 + 128, N);
    k_bnfin<<<1, 128, 0, stream>>>(s12, s12 + 128, gam + l * D128, bet + l * D128,
                                   scsh, scsh + 128, 1.f / (float)N);
    hin = yres;
  }

  // pooled readouts on RAW yres, BN affine applied to the means
  k_poolg<<<G, 256, 0, stream>>>(yres, gid, scsh, scsh + 128, outg, xcat, N);
  k_poolmg<<<M, 256, 0, stream>>>(yres, mrp, mlist, scsh, scsh + 128,
                                  xcat + (size_t)G * D128, M);

  // batched head on xcat [2560,128]: 3 GEMMs; final writes d_out directly
  dim3 g1((R + 63) / 64, 256 / 64);
  k_gemm64<<<g1, 256, 0, stream>>>(xcat, Wf, bf, fbuf, R, 128, 256, 0);
  dim3 g2((R + 63) / 64, 256 / 64);
  k_gemm64<<<g2, 256, 0, stream>>>(fbuf, W1, b1, zbuf, R, 256, 256, 1);
  dim3 g3((R + 63) / 64, 128 / 64);
  k_gemm64<<<g3, 256, 0, stream>>>(zbuf, W2, b2, outgl, R, 256, 128, 0);
}

// Round 7
// 569.385 us; speedup vs baseline: 2.0353x; 1.1924x over previous
//
#include <hip/hip_runtime.h>

// ---------------------------------------------------------------------------
// GCN forward: 3x (split-bf16 MFMA dual GEMM -> edge gather-agg -> BN-fused)
// -> CSR pooled readouts -> batched MLP head.
// Round 6: hw stored bf16 (halves gather traffic); k_agg preloads csrc
// coalesced + shfl-broadcast + 4-deep unrolled independent gathers.
// ---------------------------------------------------------------------------

#define D128 128

typedef short bf16x8 __attribute__((ext_vector_type(8)));
typedef unsigned short u16x8 __attribute__((ext_vector_type(8)));
typedef float f32x4 __attribute__((ext_vector_type(4)));

static __device__ __forceinline__ unsigned short f2bf(float x) {
  unsigned u = __float_as_uint(x);
  unsigned r = (u + 0x7FFF + ((u >> 16) & 1)) >> 16;  // RNE
  return (unsigned short)r;
}
static __device__ __forceinline__ float bf2f(unsigned short b) {
  return __uint_as_float(((unsigned)b) << 16);
}

__global__ void k_deg(const int* __restrict__ src, const int* __restrict__ dst,
                      int* __restrict__ dego, int* __restrict__ degi, int E) {
  int e = blockIdx.x * 256 + threadIdx.x;
  if (e < E) {
    atomicAdd(&dego[src[e]], 1);
    atomicAdd(&degi[dst[e]], 1);
  }
}

__global__ void k_hist_m(const int* __restrict__ mid, int* __restrict__ cntm, int N) {
  int i = blockIdx.x * 256 + threadIdx.x;
  if (i < N) atomicAdd(&cntm[mid[i]], 1);
}

__global__ void k_norm(const int* __restrict__ dego, const int* __restrict__ degi,
                       float* __restrict__ ns, float* __restrict__ nd, int N) {
  int i = blockIdx.x * 256 + threadIdx.x;
  if (i < N) {
    ns[i] = rsqrtf(fmaxf((float)dego[i], 1.f));
    nd[i] = rsqrtf(fmaxf((float)degi[i], 1.f));
  }
}

// ---- hierarchical exclusive scan: part -> scanp -> scat ----
__global__ __launch_bounds__(256) void k_part(const int* __restrict__ deg,
                                              int* __restrict__ psum, int n) {
  int b = blockIdx.x, t = threadIdx.x;
  int i = b * 1024 + t * 4;
  int4 v = make_int4(0, 0, 0, 0);
  if (i + 3 < n) v = *(const int4*)(deg + i);
  else {
    if (i < n) v.x = deg[i];
    if (i + 1 < n) v.y = deg[i + 1];
    if (i + 2 < n) v.z = deg[i + 2];
    if (i + 3 < n) v.w = deg[i + 3];
  }
  int s = v.x + v.y + v.z + v.w;
#pragma unroll
  for (int off = 1; off < 64; off <<= 1) s += __shfl_xor(s, off);
  __shared__ int wsum[4];
  if ((t & 63) == 0) wsum[t >> 6] = s;
  __syncthreads();
  if (t == 0) psum[b] = wsum[0] + wsum[1] + wsum[2] + wsum[3];
}

__global__ __launch_bounds__(1024) void k_scanp(int* __restrict__ psum, int nb) {
  __shared__ int buf[1024];
  int t = threadIdx.x;
  int v = (t < nb) ? psum[t] : 0;
  buf[t] = v;
  __syncthreads();
  for (int off = 1; off < 1024; off <<= 1) {
    int u = (t >= off) ? buf[t - off] : 0;
    __syncthreads();
    buf[t] += u;
    __syncthreads();
  }
  if (t < nb) psum[t] = buf[t] - v;
}

__global__ __launch_bounds__(256) void k_scat(const int* __restrict__ deg,
                                              const int* __restrict__ psum,
                                              int* __restrict__ rp, int n, int nb) {
  int b = blockIdx.x, t = threadIdx.x;
  int i = b * 1024 + t * 4;
  int4 v = make_int4(0, 0, 0, 0);
  if (i + 3 < n) v = *(const int4*)(deg + i);
  else {
    if (i < n) v.x = deg[i];
    if (i + 1 < n) v.y = deg[i + 1];
    if (i + 2 < n) v.z = deg[i + 2];
    if (i + 3 < n) v.w = deg[i + 3];
  }
  int s = v.x + v.y + v.z + v.w;
  __shared__ int buf[256];
  buf[t] = s;
  __syncthreads();
  for (int off = 1; off < 256; off <<= 1) {
    int u = (t >= off) ? buf[t - off] : 0;
    __syncthreads();
    buf[t] += u;
    __syncthreads();
  }
  int ex = buf[t] - s + psum[b];
  int4 o;
  o.x = ex; o.y = ex + v.x; o.z = ex + v.x + v.y; o.w = ex + v.x + v.y + v.z;
  if (i + 3 < n) *(int4*)(rp + i) = o;
  else {
    if (i < n) rp[i] = o.x;
    if (i + 1 < n) rp[i + 1] = o.y;
    if (i + 2 < n) rp[i + 2] = o.z;
    if (i + 3 < n) rp[i + 3] = o.w;
  }
  if (b == nb - 1 && t == 255) rp[n] = ex + s;
}

__global__ void k_csr(const int* __restrict__ src, const int* __restrict__ dst,
                      const int* __restrict__ rp, int* __restrict__ cur,
                      int* __restrict__ csrc, int E) {
  int e = blockIdx.x * 256 + threadIdx.x;
  if (e < E) {
    int d = dst[e];
    int p = atomicAdd(&cur[d], 1);
    csrc[rp[d] + p] = src[e];
  }
}

__global__ void k_mcsr(const int* __restrict__ mid, const int* __restrict__ mrp,
                       int* __restrict__ cur, int* __restrict__ mlist, int N) {
  int n = blockIdx.x * 256 + threadIdx.x;
  if (n < N) {
    int m = mid[n];
    int p = atomicAdd(&cur[m], 1);
    mlist[mrp[m] + p] = n;
  }
}

// pack W (3 layers x {Wg,Wr}) into MFMA B-fragment order, bf16 hi/lo.
__global__ __launch_bounds__(256) void k_wprep(const float* __restrict__ Wg,
                                               const float* __restrict__ Wr,
                                               unsigned short* __restrict__ wp) {
  int idx = blockIdx.x * 256 + threadIdx.x;
  if (idx >= 3 * 2 * 2048) return;
  int lane = idx & 63;
  int fs = (idx >> 6) & 31;
  int m = (idx >> 11) & 1;
  int l = idx >> 12;
  int cb = fs >> 2, s = fs & 3;
  const float* W = (m == 0 ? Wg : Wr) + (size_t)l * 16384;
  int n = cb * 16 + (lane & 15);
  int k0 = s * 32 + (lane >> 4) * 8;
  unsigned short* hi = wp + ((size_t)(l * 2 + m)) * 32768 + ((size_t)fs * 64 + lane) * 8;
  unsigned short* lo = hi + 16384;
#pragma unroll
  for (int j = 0; j < 8; ++j) {
    float x = W[(size_t)(k0 + j) * D128 + n];
    unsigned short h = f2bf(x);
    hi[j] = h;
    lo[j] = f2bf(x - bf2f(h));
  }
}

// split-bf16 MFMA dual GEMM: 64 rows x 256 cols (Wg|Wr) per block, 4 waves.
// hwb (bf16) = (hn @ Wg) * ns, res = relu(hn @ Wr + br), hn = h*scale+shift
__global__ __launch_bounds__(256) void k_dualmfma(
    const float* __restrict__ h, const unsigned short* __restrict__ wpl,
    const float* __restrict__ brl, const float* __restrict__ ns,
    const float* __restrict__ scale, const float* __restrict__ shift,
    unsigned short* __restrict__ hwb, float* __restrict__ res, int N) {
  __shared__ __align__(16) unsigned char smem[32768];  // hi[64][256B] | lo
  int t = threadIdx.x;
  int row0 = blockIdx.x * 64;

  // stage 64x128 f32 -> bf16 hi/lo in LDS, XOR-swizzled (byte ^= (row&7)<<4)
#pragma unroll
  for (int q = 0; q < 4; ++q) {
    int chunk = q * 256 + t;      // 1024 chunks of 8 elems
    int r = chunk >> 4;
    int c8 = chunk & 15;
    int gr = row0 + r;
    float xs[8];
    if (gr < N) {
      const float4* hp = (const float4*)(h + (size_t)gr * D128 + c8 * 8);
      float4 v0 = hp[0], v1 = hp[1];
      xs[0] = v0.x; xs[1] = v0.y; xs[2] = v0.z; xs[3] = v0.w;
      xs[4] = v1.x; xs[5] = v1.y; xs[6] = v1.z; xs[7] = v1.w;
      if (scale) {
        float4 sc0 = ((const float4*)scale)[c8 * 2];
        float4 sc1 = ((const float4*)scale)[c8 * 2 + 1];
        float4 sh0 = ((const float4*)shift)[c8 * 2];
        float4 sh1 = ((const float4*)shift)[c8 * 2 + 1];
        xs[0] = xs[0] * sc0.x + sh0.x; xs[1] = xs[1] * sc0.y + sh0.y;
        xs[2] = xs[2] * sc0.z + sh0.z; xs[3] = xs[3] * sc0.w + sh0.w;
        xs[4] = xs[4] * sc1.x + sh1.x; xs[5] = xs[5] * sc1.y + sh1.y;
        xs[6] = xs[6] * sc1.z + sh1.z; xs[7] = xs[7] * sc1.w + sh1.w;
      }
    } else {
#pragma unroll
      for (int j = 0; j < 8; ++j) xs[j] = 0.f;
    }
    u16x8 hi8, lo8;
#pragma unroll
    for (int j = 0; j < 8; ++j) {
      unsigned short hb = f2bf(xs[j]);
      hi8[j] = hb;
      lo8[j] = f2bf(xs[j] - bf2f(hb));
    }
    int sw = (c8 * 16) ^ ((r & 7) << 4);
    *(u16x8*)(&smem[r * 256 + sw]) = hi8;
    *(u16x8*)(&smem[16384 + r * 256 + sw]) = lo8;
  }
  __syncthreads();

  int w = t >> 6, l6 = t & 63;
  int mat = w >> 1, half = w & 1;
  const unsigned short* wpm = wpl + (size_t)mat * 32768;

  f32x4 acc[4][4];
#pragma unroll
  for (int rb = 0; rb < 4; ++rb)
#pragma unroll
    for (int cb = 0; cb < 4; ++cb) acc[rb][cb] = (f32x4){0.f, 0.f, 0.f, 0.f};

#pragma unroll
  for (int s = 0; s < 4; ++s) {
    bf16x8 ah[4], al[4];
    int kb = s * 64 + (l6 >> 4) * 16;
#pragma unroll
    for (int rb = 0; rb < 4; ++rb) {
      int row = rb * 16 + (l6 & 15);
      int off = row * 256 + (kb ^ ((row & 7) << 4));
      ah[rb] = *(const bf16x8*)(&smem[off]);
      al[rb] = *(const bf16x8*)(&smem[16384 + off]);
    }
    bf16x8 bh[4], bl[4];
#pragma unroll
    for (int cb = 0; cb < 4; ++cb) {
      const unsigned short* p = wpm + (((size_t)(half * 4 + cb) * 4 + s) * 64 + l6) * 8;
      bh[cb] = *(const bf16x8*)p;
      bl[cb] = *(const bf16x8*)(p + 16384);
    }
#pragma unroll
    for (int rb = 0; rb < 4; ++rb)
#pragma unroll
      for (int cb = 0; cb < 4; ++cb) {
        acc[rb][cb] = __builtin_amdgcn_mfma_f32_16x16x32_bf16(ah[rb], bh[cb], acc[rb][cb], 0, 0, 0);
        acc[rb][cb] = __builtin_amdgcn_mfma_f32_16x16x32_bf16(al[rb], bh[cb], acc[rb][cb], 0, 0, 0);
        acc[rb][cb] = __builtin_amdgcn_mfma_f32_16x16x32_bf16(ah[rb], bl[cb], acc[rb][cb], 0, 0, 0);
      }
  }

  // epilogue: D row = (l6>>4)*4 + reg, col = l6&15  (m89-verified)
  int rsub = (l6 >> 4) * 4;
  int colb = half * 64 + (l6 & 15);
  if (mat == 0) {
#pragma unroll
    for (int rb = 0; rb < 4; ++rb)
#pragma unroll
      for (int reg = 0; reg < 4; ++reg) {
        int gr = row0 + rb * 16 + rsub + reg;
        if (gr >= N) continue;
        float sv = ns[gr];
        unsigned short* op = hwb + ((size_t)gr << 7) + colb;
#pragma unroll
        for (int cb = 0; cb < 4; ++cb) op[cb * 16] = f2bf(acc[rb][cb][reg] * sv);
      }
  } else {
    float bv[4];
#pragma unroll
    for (int cb = 0; cb < 4; ++cb) bv[cb] = brl[colb + cb * 16];
#pragma unroll
    for (int rb = 0; rb < 4; ++rb)
#pragma unroll
      for (int reg = 0; reg < 4; ++reg) {
        int gr = row0 + rb * 16 + rsub + reg;
        if (gr >= N) continue;
        float* op = res + (size_t)gr * D128 + colb;
#pragma unroll
        for (int cb = 0; cb < 4; ++cb) op[cb * 16] = fmaxf(acc[rb][cb][reg] + bv[cb], 0.f);
      }
  }
}

// one wave per node: y = relu(agg*nd + bg) + res, written over res (yres)
// csrc preloaded coalesced + shfl-broadcast; gathers unrolled 4-deep.
__global__ __launch_bounds__(256) void k_agg(
    const unsigned short* __restrict__ hwb, const int* __restrict__ rp,
    const int* __restrict__ csrc, const float* __restrict__ nd,
    const float* __restrict__ bgl, float* __restrict__ yres, int N) {
  int n = blockIdx.x * 4 + (threadIdx.x >> 6);
  int lane = threadIdx.x & 63;
  if (n >= N) return;
  int beg = rp[n], end = rp[n + 1];
  float ax = 0.f, ay = 0.f;
  for (int e0 = beg; e0 < end; e0 += 64) {
    int cnt = min(end - e0, 64);
    int sreg = (lane < cnt) ? csrc[e0 + lane] : 0;
    int j = 0;
    for (; j + 4 <= cnt; j += 4) {
      int s0 = __shfl(sreg, j);
      int s1 = __shfl(sreg, j + 1);
      int s2 = __shfl(sreg, j + 2);
      int s3 = __shfl(sreg, j + 3);
      unsigned v0 = *(const unsigned*)(hwb + (((size_t)s0) << 7) + lane * 2);
      unsigned v1 = *(const unsigned*)(hwb + (((size_t)s1) << 7) + lane * 2);
      unsigned v2 = *(const unsigned*)(hwb + (((size_t)s2) << 7) + lane * 2);
      unsigned v3 = *(const unsigned*)(hwb + (((size_t)s3) << 7) + lane * 2);
      ax += bf2f((unsigned short)(v0 & 0xffffu)) + bf2f((unsigned short)(v1 & 0xffffu))
          + bf2f((unsigned short)(v2 & 0xffffu)) + bf2f((unsigned short)(v3 & 0xffffu));
      ay += bf2f((unsigned short)(v0 >> 16)) + bf2f((unsigned short)(v1 >> 16))
          + bf2f((unsigned short)(v2 >> 16)) + bf2f((unsigned short)(v3 >> 16));
    }
    for (; j < cnt; ++j) {
      int s = __shfl(sreg, j);
      unsigned v = *(const unsigned*)(hwb + (((size_t)s) << 7) + lane * 2);
      ax += bf2f((unsigned short)(v & 0xffffu));
      ay += bf2f((unsigned short)(v >> 16));
    }
  }
  float ndv = nd[n];
  float2 b = ((const float2*)bgl)[lane];
  float2 r = ((const float2*)yres)[(size_t)n * 64 + lane];
  float2 y;
  y.x = fmaxf(ax * ndv + b.x, 0.f) + r.x;
  y.y = fmaxf(ay * ndv + b.y, 0.f) + r.y;
  ((float2*)yres)[(size_t)n * 64 + lane] = y;
}

__global__ __launch_bounds__(256) void k_stats(const float* __restrict__ y,
                                               float* __restrict__ s1,
                                               float* __restrict__ s2, int N) {
  int t = threadIdx.x;
  int col = t & 127, half = t >> 7;
  float a = 0.f, q = 0.f;
  for (int r = blockIdx.x * 2 + half; r < N; r += gridDim.x * 2) {
    float v = y[(size_t)r * D128 + col];
    a += v; q += v * v;
  }
  __shared__ float ls[256], lq[256];
  ls[t] = a; lq[t] = q;
  __syncthreads();
  if (t < 128) {
    atomicAdd(&s1[col], ls[t] + ls[t + 128]);
    atomicAdd(&s2[col], lq[t] + lq[t + 128]);
  }
}

__global__ void k_bnfin(const float* __restrict__ s1, const float* __restrict__ s2,
                        const float* __restrict__ gam, const float* __restrict__ bet,
                        float* __restrict__ scale, float* __restrict__ shift, float invN) {
  int j = threadIdx.x;
  float mu = s1[j] * invN;
  float var = s2[j] * invN - mu * mu;
  float sc = gam[j] * rsqrtf(var + 1e-5f);
  scale[j] = sc;
  shift[j] = bet[j] - mu * sc;
}

// graph pooling on RAW yres, BN affine applied to means; writes d_out + xcat
__global__ __launch_bounds__(256) void k_poolg(const float* __restrict__ y,
                                               const int* __restrict__ gid,
                                               const float* __restrict__ scale,
                                               const float* __restrict__ shift,
                                               float* __restrict__ out,
                                               float* __restrict__ xcat, int N) {
  int g = blockIdx.x;
  int lo = 0, hi = N;
  while (lo < hi) { int m = (lo + hi) >> 1; if (gid[m] < g) lo = m + 1; else hi = m; }
  int beg = lo;
  hi = N;
  while (lo < hi) { int m = (lo + hi) >> 1; if (gid[m] <= g) lo = m + 1; else hi = m; }
  int end = lo;
  int t = threadIdx.x;
  int col = t & 127, half = t >> 7;
  float acc = 0.f;
  for (int r = beg + half; r < end; r += 2) acc += y[(size_t)r * D128 + col];
  __shared__ float ls[256];
  ls[t] = acc;
  __syncthreads();
  if (t < 128) {
    float v = ls[t] + ls[t + 128];
    v = v / fmaxf((float)(end - beg), 1.f);
    v = v * scale[t] + shift[t];
    out[(size_t)g * D128 + t] = v;
    xcat[(size_t)g * D128 + t] = v;
  }
}

// motif pooling via CSR gather: one block per motif m in [1..M]
__global__ __launch_bounds__(256) void k_poolmg(const float* __restrict__ y,
                                                const int* __restrict__ mrp,
                                                const int* __restrict__ mlist,
                                                const float* __restrict__ scale,
                                                const float* __restrict__ shift,
                                                float* __restrict__ xsub, int M) {
  int m = blockIdx.x + 1;
  int beg = mrp[m], end = mrp[m + 1];
  int t = threadIdx.x;
  int col = t & 127, half = t >> 7;
  float acc = 0.f;
  for (int r = beg + half; r < end; r += 2) {
    int n = mlist[r];
    acc += y[(size_t)n * D128 + col];
  }
  __shared__ float ls[256];
  ls[t] = acc;
  __syncthreads();
  if (t < 128) {
    float v = ls[t] + ls[t + 128];
    v = v / fmaxf((float)(end - beg), 1.f);
    v = v * scale[t] + shift[t];
    xsub[(size_t)(m - 1) * D128 + t] = v;
  }
}

// tiled GEMM: out = act(X[M,K] @ W[K,N] + b), BM=64 BN=64 BK=32, 256 thr, 4x4/thr
__global__ __launch_bounds__(256) void k_gemm64(
    const float* __restrict__ X, const float* __restrict__ W,
    const float* __restrict__ b, float* __restrict__ out,
    int Mrows, int K, int Ncols, int relu) {
  __shared__ float xs[64][33];
  __shared__ float ws[32][68];
  int t = threadIdx.x;
  int row0 = blockIdx.x * 64, col0 = blockIdx.y * 64;
  int tx = t & 15, ty = t >> 4;
  int j0 = tx * 4, r0 = ty * 4;
  float acc[4][4] = {};
  for (int k0 = 0; k0 < K; k0 += 32) {
    for (int i = t; i < 512; i += 256) {
      int r = i >> 3, c4 = i & 7;
      int gr = row0 + r;
      float4 v = make_float4(0.f, 0.f, 0.f, 0.f);
      if (gr < Mrows) v = *(const float4*)(X + (size_t)gr * K + k0 + c4 * 4);
      xs[r][c4 * 4 + 0] = v.x; xs[r][c4 * 4 + 1] = v.y;
      xs[r][c4 * 4 + 2] = v.z; xs[r][c4 * 4 + 3] = v.w;
    }
    for (int i = t; i < 512; i += 256) {
      int r = i >> 4, c4 = i & 15;
      float4 v = *(const float4*)(W + (size_t)(k0 + r) * Ncols + col0 + c4 * 4);
      *(float4*)(&ws[r][c4 * 4]) = v;
    }
    __syncthreads();
#pragma unroll
    for (int kk = 0; kk < 32; ++kk) {
      float a_[4];
#pragma unroll
      for (int r = 0; r < 4; ++r) a_[r] = xs[r0 + r][kk];
      float4 wv = *(const float4*)(&ws[kk][j0]);
      float b_[4] = {wv.x, wv.y, wv.z, wv.w};
#pragma unroll
      for (int r = 0; r < 4; ++r)
#pragma unroll
        for (int j = 0; j < 4; ++j) acc[r][j] += a_[r] * b_[j];
    }
    __syncthreads();
  }
  float4 bb = *(const float4*)(b + col0 + j0);
  float ba[4] = {bb.x, bb.y, bb.z, bb.w};
#pragma unroll
  for (int r = 0; r < 4; ++r) {
    int gr = row0 + r0 + r;
    if (gr >= Mrows) continue;
    float4 o;
    o.x = acc[r][0] + ba[0]; o.y = acc[r][1] + ba[1];
    o.z = acc[r][2] + ba[2]; o.w = acc[r][3] + ba[3];
    if (relu) {
      o.x = fmaxf(o.x, 0.f); o.y = fmaxf(o.y, 0.f);
      o.z = fmaxf(o.z, 0.f); o.w = fmaxf(o.w, 0.f);
    }
    *(float4*)(out + (size_t)gr * Ncols + col0 + j0) = o;
  }
}

extern "C" void kernel_launch(void* const* d_in, const int* in_sizes, int n_in,
                              void* d_out, int out_size, void* d_ws, size_t ws_size,
                              hipStream_t stream) {
  (void)n_in; (void)out_size; (void)ws_size;
  const float* nf   = (const float*)d_in[0];
  const int*   src  = (const int*)d_in[1];
  const int*   dst  = (const int*)d_in[2];
  const int*   gid  = (const int*)d_in[3];
  const int*   mid  = (const int*)d_in[4];
  const float* Wg   = (const float*)d_in[5];
  const float* bg   = (const float*)d_in[6];
  const float* Wr   = (const float*)d_in[7];
  const float* br   = (const float*)d_in[8];
  const float* gam  = (const float*)d_in[9];
  const float* bet  = (const float*)d_in[10];
  const float* Wf   = (const float*)d_in[11];
  const float* bf   = (const float*)d_in[12];
  const float* W1   = (const float*)d_in[13];
  const float* b1   = (const float*)d_in[14];
  const float* W2   = (const float*)d_in[15];
  const float* b2   = (const float*)d_in[16];

  const int N = in_sizes[0] / D128;
  const int E = in_sizes[1];
  const int G = 512;
  const int M = 2048;
  const int R = G + M;  // 2560 batched head rows

  char* ws = (char*)d_ws;
  size_t off = 0;
  auto alloc = [&](size_t bytes) -> void* {
    void* p = ws + off;
    off = (off + bytes + 255) & ~(size_t)255;
    return p;
  };
  unsigned short* hwb = (unsigned short*)alloc((size_t)N * D128 * 2);
  float* yres = (float*)alloc((size_t)N * D128 * 4);
  // one contiguous zero block: dego | degi | cur | cntm | mcur
  int*   zblk = (int*)alloc((size_t)(3 * N + 2 * (M + 1)) * 4);
  int*   dego = zblk;
  int*   degi = zblk + N;
  int*   cur  = zblk + 2 * N;
  int*   cntm = zblk + 3 * N;
  int*   mcur = zblk + 3 * N + (M + 1);
  float* ns   = (float*)alloc((size_t)N * 4);
  float* nd   = (float*)alloc((size_t)N * 4);
  int*   rp   = (int*)alloc((size_t)(N + 1) * 4);
  int*   mrp  = (int*)alloc((size_t)(M + 2) * 4);
  int*   csrc = (int*)alloc((size_t)E * 4);
  int*   mlist= (int*)alloc((size_t)N * 4);
  int*   psum = (int*)alloc(1024 * 4);
  float* s12  = (float*)alloc(256 * 4);
  float* scsh = (float*)alloc(256 * 4);
  unsigned short* wp = (unsigned short*)alloc((size_t)3 * 2 * 2 * 16384 * 2);
  float* xcat = (float*)alloc((size_t)R * D128 * 4);
  float* fbuf = (float*)alloc((size_t)R * 256 * 4);
  float* zbuf = (float*)alloc((size_t)R * 256 * 4);

  float* outg  = (float*)d_out;             // graph_feats [512,128]
  float* outgl = outg + (size_t)G * D128;   // out_global [512,128] then out_sub [2048,128]

  hipMemsetAsync(zblk, 0, (size_t)(3 * N + 2 * (M + 1)) * 4, stream);

  k_deg<<<(E + 255) / 256, 256, 0, stream>>>(src, dst, dego, degi, E);
  k_hist_m<<<(N + 255) / 256, 256, 0, stream>>>(mid, cntm, N);
  k_norm<<<(N + 255) / 256, 256, 0, stream>>>(dego, degi, ns, nd, N);
  k_wprep<<<(3 * 2 * 2048 + 255) / 256, 256, 0, stream>>>(Wg, Wr, wp);

  // hierarchical scan: degi -> rp
  int nb1 = (N + 1023) / 1024;
  k_part<<<nb1, 256, 0, stream>>>(degi, psum, N);
  k_scanp<<<1, 1024, 0, stream>>>(psum, nb1);
  k_scat<<<nb1, 256, 0, stream>>>(degi, psum, rp, N, nb1);
  k_csr<<<(E + 255) / 256, 256, 0, stream>>>(src, dst, rp, cur, csrc, E);

  // hierarchical scan: cntm -> mrp
  int nb2 = (M + 1 + 1023) / 1024;
  k_part<<<nb2, 256, 0, stream>>>(cntm, psum, M + 1);
  k_scanp<<<1, 1024, 0, stream>>>(psum, nb2);
  k_scat<<<nb2, 256, 0, stream>>>(cntm, psum, mrp, M + 1, nb2);
  k_mcsr<<<(N + 255) / 256, 256, 0, stream>>>(mid, mrp, mcur, mlist, N);

  const float* hin = nf;
  for (int l = 0; l < 3; ++l) {
    const float* sc = (l == 0) ? nullptr : scsh;
    const float* sh = (l == 0) ? nullptr : (scsh + 128);
    k_dualmfma<<<(N + 63) / 64, 256, 0, stream>>>(hin, wp + (size_t)l * 65536,
                                                  br + l * D128, ns, sc, sh, hwb, yres, N);
    k_agg<<<(N + 3) / 4, 256, 0, stream>>>(hwb, rp, csrc, nd, bg + l * D128, yres, N);
    hipMemsetAsync(s12, 0, 256 * 4, stream);
    k_stats<<<256, 256, 0, stream>>>(yres, s12, s12 + 128, N);
    k_bnfin<<<1, 128, 0, stream>>>(s12, s12 + 128, gam + l * D128, bet + l * D128,
                                   scsh, scsh + 128, 1.f / (float)N);
    hin = yres;
  }

  // pooled readouts on RAW yres, BN affine applied to the means
  k_poolg<<<G, 256, 0, stream>>>(yres, gid, scsh, scsh + 128, outg, xcat, N);
  k_poolmg<<<M, 256, 0, stream>>>(yres, mrp, mlist, scsh, scsh + 128,
                                  xcat + (size_t)G * D128, M);

  // batched head on xcat [2560,128]: 3 GEMMs; final writes d_out directly
  dim3 g1((R + 63) / 64, 256 / 64);
  k_gemm64<<<g1, 256, 0, stream>>>(xcat, Wf, bf, fbuf, R, 128, 256, 0);
  dim3 g2((R + 63) / 64, 256 / 64);
  k_gemm64<<<g2, 256, 0, stream>>>(fbuf, W1, b1, zbuf, R, 256, 256, 1);
  dim3 g3((R + 63) / 64, 128 / 64);
  k_gemm64<<<g3, 256, 0, stream>>>(zbuf, W2, b2, outgl, R, 256, 128, 0);
}